// Round 4
// baseline (1802.187 us; speedup 1.0000x reference)
//
#include <hip/hip_runtime.h>

#define DEVI __device__ __forceinline__

static constexpr int BB=4, CC=128, LLn=4096, DI=256, NS=16, RR=8, SS=4;
static constexpr int PP = RR + 2*NS;            // 40
static constexpr int CT = 64, NCH = LLn/CT;     // scan staging: 64 chunks of 64
static constexpr size_t BLC  = (size_t)BB*LLn*CC;    // 2,097,152
static constexpr size_t BLD  = (size_t)BB*LLn*DI;    // 4,194,304
static constexpr size_t SBLD = (size_t)SS*BLD;
static constexpr size_t SBLP = (size_t)SS*BB*LLn*PP;

// ---- weight offsets inside ws (floats), padded to multiples of 4 ----
static constexpr int OW_LN1W=0, OW_LN1B=128, OW_LN2W=256, OW_LN2B=384, OW_LN3W=512, OW_LN3B=640,
 OW_SPW=768, OW_CAW1=820, OW_CAW2=4916, OW_DWW=9012, OW_DWB=10164, OW_IPW=10292,
 OW_IP1W=75828, OW_IP2W=108596, OW_CVW=141364, OW_CVB=145460, OW_XPW=146484,
 OW_DTW=187444, OW_DTB=195636, OW_ALOG=196660, OW_DSK=213044, OW_OUTW=214068;
static constexpr int NW_RAW = 246836;   // last tensor end
static constexpr int NW_END = 246848;   // padded

__constant__ int c_woff[22] = {OW_LN1W,OW_LN1B,OW_LN2W,OW_LN2B,OW_LN3W,OW_LN3B,OW_SPW,OW_CAW1,
 OW_CAW2,OW_DWW,OW_DWB,OW_IPW,OW_IP1W,OW_IP2W,OW_CVW,OW_CVB,OW_XPW,OW_DTW,OW_DTB,OW_ALOG,
 OW_DSK,OW_OUTW};
__constant__ int c_wsz[22]  = {128,128,128,128,128,128,50,4096,4096,1152,128,65536,32768,32768,
 4096,1024,40960,8192,1024,16384,1024,32768};

// ---- workspace layout (float offsets) ----
static constexpr size_t O_XF   = NW_END;
static constexpr size_t O_E1   = O_XF + BLC;
static constexpr size_t O_E2   = O_E1 + BLC;
static constexpr size_t O_Z    = O_E2 + BLC;          // later reused for gated g
static constexpr size_t O_U    = O_Z + BLD;           // u streams; later reused for y
static constexpr size_t O_UC   = O_U + SBLD;
static constexpr size_t O_PROJ = O_UC + SBLD;
static constexpr size_t O_SDT  = O_PROJ + SBLP;
static constexpr size_t O_H    = O_SDT + (size_t)SS*BB*NCH*DI;
static constexpr size_t O_M    = O_H + (size_t)SS*BB*NCH*DI*NS;
static constexpr size_t O_S    = O_M + 2*(size_t)BB*2*LLn;
static constexpr size_t O_GF   = O_S + 2*(size_t)BB*LLn;
static constexpr size_t O_PART = O_GF + BLC;
static constexpr size_t O_SIG  = O_PART + 2*(size_t)BB*32*CC;
static constexpr size_t WS_END = O_SIG + (size_t)BB*CC;

// ---- helpers ----
DEVI float bfu2f(unsigned short s){ union{unsigned u; float f;} c; c.u = ((unsigned)s)<<16; return c.f; }
DEVI bool bfmode(const void* ln1w){ return *(const unsigned*)ln1w == 0x3F803F80u; }
DEVI float2 ldin2(const void* p, int i, bool isbf){
  if(isbf){ unsigned v = *(const unsigned*)((const unsigned short*)p + i);
    return make_float2(bfu2f((unsigned short)(v & 0xFFFFu)), bfu2f((unsigned short)(v >> 16))); }
  const float* f = (const float*)p + i; return make_float2(f[0], f[1]);
}
DEVI float wsum(float v){
#pragma unroll
  for(int o=32;o;o>>=1) v += __shfl_xor(v,o,64);
  return v; }
DEVI float wmaxr(float v){
#pragma unroll
  for(int o=32;o;o>>=1) v = fmaxf(v, __shfl_xor(v,o,64));
  return v; }
DEVI float sigf(float x){ return 1.f/(1.f+__expf(-x)); }
// layernorm over 128 channels held as 2 values/lane across one 64-lane wave
DEVI float2 ln_wave(float2 x, const float* Wf, int ow, int ob, int lane){
  float mu = wsum(x.x + x.y) * (1.f/(float)CC);
  float dx = x.x - mu, dy = x.y - mu;
  float var = wsum(dx*dx + dy*dy) * (1.f/(float)CC);
  float rs = rsqrtf(var + 1e-5f);
  int c = 2*lane;
  return make_float2(dx*rs*Wf[ow+c] + Wf[ob+c], dy*rs*Wf[ow+c+1] + Wf[ob+c+1]);
}

struct Srcs { const void* p[22]; };

// K0: convert all weight tensors to f32 workspace
__global__ void k_wcvt(Srcs s, float* __restrict__ ws){
  bool isbf = bfmode(s.p[0]);
  int idx = blockIdx.x*256 + threadIdx.x;
  if(idx >= NW_RAW) return;
  int t = 0;
  while(t < 21 && idx >= c_woff[t+1]) t++;
  int j = idx - c_woff[t];
  if(j >= c_wsz[t]) return;  // padding gap
  float v = isbf ? bfu2f(((const unsigned short*)s.p[t])[j]) : ((const float*)s.p[t])[j];
  ws[idx] = v;
}

// K1: fusion_resi = fusion + fusion_resi -> out1(f32); xf = ln1(ln1(fr))
__global__ void k_fuse(const void* fus, const void* fres, const void* ln1raw,
                       float* __restrict__ ws, float* __restrict__ outf){
  bool isbf = bfmode(ln1raw);
  int lane = threadIdx.x & 63, wv = threadIdx.x >> 6;
  int row = blockIdx.x*4 + wv;              // 16384 rows
  int base = row*CC;
  float2 a = ldin2(fus, base+2*lane, isbf);
  float2 b = ldin2(fres, base+2*lane, isbf);
  float2 fr = make_float2(a.x+b.x, a.y+b.y);
  *(float2*)(outf + BLC + base + 2*lane) = fr;      // output 1 = fusion_resi (f32)
  float2 y = ln_wave(fr, ws, OW_LN1W, OW_LN1B, lane);
  y = ln_wave(y, ws, OW_LN1W, OW_LN1B, lane);
  *(float2*)(ws + O_XF + base + 2*lane) = y;
}

// K2a: per-pixel channel mean/max of I1 (ten=0) and I2 (ten=1)
__global__ void k_meanmax(const void* I1, const void* I2, const void* ln1raw, float* __restrict__ ws){
  bool isbf = bfmode(ln1raw);
  int lane = threadIdx.x & 63, wv = threadIdx.x >> 6;
  int g = blockIdx.x*4 + wv;                // 32768 waves
  int ten = g & 1, row = g >> 1;
  const void* src = ten ? I2 : I1;
  float2 x = ldin2(src, row*CC + 2*lane, isbf);
  float sm = wsum(x.x + x.y) * (1.f/(float)CC);
  float mx = wmaxr(fmaxf(x.x, x.y));
  if(lane == 0){
    int b = row >> 12, l = row & 4095;
    float* mt = ws + O_M + (size_t)ten*(BB*2*LLn);
    mt[(size_t)b*2*LLn + l] = sm;
    mt[(size_t)b*2*LLn + LLn + l] = mx;
  }
}

// K2b: 5x5 conv (2ch->1) + sigmoid -> s1,s2
__global__ void k_spconv(float* __restrict__ ws){
  int idx = blockIdx.x*256 + threadIdx.x;   // 32768
  int ten = idx >> 14, b = (idx>>12)&3, l = idx & 4095;
  int h = l >> 6, w = l & 63;
  const float* mt = ws + O_M + (size_t)ten*(BB*2*LLn) + (size_t)b*2*LLn;
  float acc = 0.f;
  for(int ci=0; ci<2; ci++)
    for(int kh=0; kh<5; kh++){
      int hh = h + kh - 2; if((unsigned)hh >= 64u) continue;
      for(int kw=0; kw<5; kw++){
        int wn = w + kw - 2; if((unsigned)wn >= 64u) continue;
        acc += mt[(size_t)ci*LLn + hh*64 + wn] * ws[OW_SPW + ci*25 + kh*5 + kw];
      }
    }
  ws[O_S + (size_t)ten*(BB*LLn) + (size_t)b*LLn + l] = sigf(acc);
}

// K2c: e1 = ln2(ln2(I2*s2)), e2 = ln3(ln3(I1*s1))
__global__ void k_escale(const void* I1, const void* I2, const void* ln1raw, float* __restrict__ ws){
  bool isbf = bfmode(ln1raw);
  int lane = threadIdx.x & 63, wv = threadIdx.x >> 6;
  int g = blockIdx.x*4 + wv;
  int ten = g & 1, row = g >> 1;            // ten0: e1 from I2; ten1: e2 from I1
  const void* src = ten ? I1 : I2;
  float sc = ws[O_S + (ten ? 0 : (size_t)BB*LLn) + row];
  float2 x = ldin2(src, row*CC + 2*lane, isbf);
  x.x *= sc; x.y *= sc;
  int ow = ten ? OW_LN3W : OW_LN2W, ob = ten ? OW_LN3B : OW_LN2B;
  float2 y = ln_wave(x, ws, ow, ob, lane);
  y = ln_wave(y, ws, ow, ob, lane);
  float* dst = ws + (ten ? O_E2 : O_E1);
  *(float2*)(dst + row*CC + 2*lane) = y;
}

// K3: f32 GEMM  out[m,n] = sum_k A[m,k]*Wt[n,k]; 64x64 tile, transposed LDS
__global__ __launch_bounds__(256) void k_gemm(const float* __restrict__ A, const float* __restrict__ Wt,
    float* __restrict__ out, int Kd, int N, int mode, float* __restrict__ u, float* __restrict__ z){
  __shared__ float As[64][68];
  __shared__ float Bs[64][68];
  const int tx = threadIdx.x & 15, ty = threadIdx.x >> 4;
  const int n0 = blockIdx.x * 64, m0 = blockIdx.y * 64;
  float acc[4][4] = {};
  const int nk = Kd >> 6;
  for(int kt=0; kt<nk; kt++){
#pragma unroll
    for(int i=0;i<16;i++){
      int idx = i*256 + threadIdx.x; int r = idx>>6, c = idx&63;
      As[c][r] = A[(size_t)(m0+r)*Kd + kt*64 + c];
      Bs[c][r] = Wt[(size_t)(n0+r)*Kd + kt*64 + c];
    }
    __syncthreads();
#pragma unroll 8
    for(int k=0;k<64;k++){
      float4 a4 = *(const float4*)&As[k][ty*4];
      float4 b4 = *(const float4*)&Bs[k][tx*4];
      float av[4] = {a4.x,a4.y,a4.z,a4.w};
      float bv[4] = {b4.x,b4.y,b4.z,b4.w};
#pragma unroll
      for(int i=0;i<4;i++)
#pragma unroll
        for(int j=0;j<4;j++) acc[i][j] += av[i]*bv[j];
    }
    __syncthreads();
  }
#pragma unroll
  for(int i=0;i<4;i++){
    int m = m0 + ty*4 + i;
    float4 v = make_float4(acc[i][0],acc[i][1],acc[i][2],acc[i][3]);
    int n = n0 + tx*4;
    if(mode == 0){
      *(float4*)&out[(size_t)m*N + n] = v;
    } else {  // in-proj split: u0, reversed u1, z
      int b = m >> 12, l = m & (LLn-1);
      if(n < DI){
        *(float4*)&u[((size_t)b*LLn + l)*DI + n] = v;
        *(float4*)&u[((size_t)(BB + b)*LLn + (LLn-1-l))*DI + n] = v;
      } else {
        *(float4*)&z[((size_t)b*LLn + l)*DI + (n-DI)] = v;
      }
    }
  }
}

// K4: causal depthwise conv (K=4) + bias + SiLU
__global__ void k_convsilu(float* __restrict__ ws){
  int t = blockIdx.x*256 + threadIdx.x;     // SBLD/4
  int d4 = t & 63, l = (t>>6)&4095, sb = t>>18, s = sb>>2;
  int d0 = d4*4;
  const float* wp = ws + OW_CVW + ((size_t)s*DI + d0)*4;
  float wv[16];
#pragma unroll
  for(int q=0;q<16;q++) wv[q] = wp[q];
  float4 acc = *(const float4*)&ws[OW_CVB + s*DI + d0];
  size_t rb = ((size_t)sb*LLn)*DI;
#pragma unroll
  for(int k=0;k<4;k++){
    int lk = l - 3 + k;
    if(lk >= 0){
      float4 uv = *(const float4*)&ws[O_U + rb + (size_t)lk*DI + d0];
      acc.x += wv[0*4+k]*uv.x; acc.y += wv[1*4+k]*uv.y;
      acc.z += wv[2*4+k]*uv.z; acc.w += wv[3*4+k]*uv.w;
    }
  }
  acc.x *= sigf(acc.x); acc.y *= sigf(acc.y); acc.z *= sigf(acc.z); acc.w *= sigf(acc.w);
  *(float4*)&ws[O_UC + rb + (size_t)l*DI + d0] = acc;
}

// K5: proj[row,p] = sum_d uc[row,d]*xproj_w[s,p,d]
__global__ __launch_bounds__(256) void k_xproj(float* __restrict__ ws){
  __shared__ float ucl[16][260];
  __shared__ float wl[PP][260];
  int r0 = blockIdx.x * 16;                 // rows of 65536
  int s = r0 >> 14;
#pragma unroll
  for(int i=0;i<4;i++){
    int e4 = i*256 + threadIdx.x; int r = e4>>6, c4 = e4&63;
    *(float4*)&ucl[r][c4*4] = *(const float4*)&ws[O_UC + (size_t)(r0+r)*DI + c4*4];
  }
#pragma unroll
  for(int i=0;i<10;i++){
    int e4 = i*256 + threadIdx.x; int r = e4>>6, c4 = e4&63;
    *(float4*)&wl[r][c4*4] = *(const float4*)&ws[OW_XPW + ((size_t)s*PP + r)*DI + c4*4];
  }
  __syncthreads();
  int r = threadIdx.x & 15, ps = threadIdx.x >> 4;
  for(int pp=0; pp<3; pp++){
    int p = ps + pp*16;
    if(p < PP){
      float4 acc = make_float4(0,0,0,0);
#pragma unroll 8
      for(int c4=0;c4<64;c4++){
        float4 a = *(const float4*)&ucl[r][c4*4];
        float4 b = *(const float4*)&wl[p][c4*4];
        acc.x += a.x*b.x; acc.y += a.y*b.y; acc.z += a.z*b.z; acc.w += a.w*b.w;
      }
      ws[O_PROJ + (size_t)(r0+r)*PP + p] = acc.x+acc.y+acc.z+acc.w;
    }
  }
}

// K6: REFERENCE-STRUCTURE sequential scan. One block per (s,b); thread = d.
__global__ __launch_bounds__(256) void k_scan_seq(float* __restrict__ ws){
  __shared__ float pl[CT*PP];
  int sb = blockIdx.x, s = sb >> 2;
  int d = threadIdx.x;
  float dtw[RR];
#pragma unroll
  for(int r=0;r<RR;r++) dtw[r] = ws[OW_DTW + ((size_t)s*DI + d)*RR + r];
  float dtb = ws[OW_DTB + s*DI + d];
  float an2[NS]; bool fast = true;
#pragma unroll
  for(int n=0;n<NS;n++){
    float a = -__expf(ws[OW_ALOG + ((size_t)s*DI + d)*NS + n]);
    an2[n] = a * 1.44269504f;
    fast = fast && (fabsf(a + (float)(n+1)) < 1e-4f);
  }
  float dsk = ws[OW_DSK + s*DI + d];
  float h[NS];
#pragma unroll
  for(int n=0;n<NS;n++) h[n] = 0.f;
  for(int ch=0; ch<NCH; ch++){
    __syncthreads();
    size_t prow = ((size_t)sb*LLn + (size_t)ch*CT)*PP;
#pragma unroll
    for(int i=0;i<10;i++){ int idx = i*256 + threadIdx.x; pl[idx] = ws[O_PROJ + prow + idx]; }
    __syncthreads();
    size_t ub = ((size_t)sb*LLn + (size_t)ch*CT)*DI + d;
    if(fast){
      for(int ll=0; ll<CT; ll++){
        const float* pr = &pl[ll*PP];
        float x = dtb;
#pragma unroll
        for(int r=0;r<RR;r++) x += pr[r]*dtw[r];
        float dt = (x > 15.f) ? x : __logf(1.f + __expf(x));
        float ut = ws[O_UC + ub + (size_t)ll*DI];
        float du = dt*ut;
        float e = __expf(-dt), da = e;
        float y = 0.f;
#pragma unroll
        for(int n=0;n<NS;n++){ h[n] = h[n]*da + du*pr[RR+n]; y += h[n]*pr[RR+NS+n]; da *= e; }
        ws[O_U + ub + (size_t)ll*DI] = y + ut*dsk;
      }
    } else {
      for(int ll=0; ll<CT; ll++){
        const float* pr = &pl[ll*PP];
        float x = dtb;
#pragma unroll
        for(int r=0;r<RR;r++) x += pr[r]*dtw[r];
        float dt = (x > 15.f) ? x : __logf(1.f + __expf(x));
        float ut = ws[O_UC + ub + (size_t)ll*DI];
        float du = dt*ut;
        float y = 0.f;
#pragma unroll
        for(int n=0;n<NS;n++){ float da = exp2f(an2[n]*dt); h[n] = h[n]*da + du*pr[RR+n]; y += h[n]*pr[RR+NS+n]; }
        ws[O_U + ub + (size_t)ll*DI] = y + ut*dsk;
      }
    }
  }
}

// K9: combine 4 streams (stream1 re-reversed) and gate with silu(z); write into z buffer
__global__ void k_gate(float* __restrict__ ws){
  int t = blockIdx.x*256 + threadIdx.x;     // BLD/4
  int d4 = t & 63, l = (t>>6)&4095, b = t>>18;
  int d0 = d4*4;
  const float* y = ws + O_U;
  size_t i0 = ((size_t)(0*BB+b)*LLn + l)*DI + d0;
  size_t i1 = ((size_t)(1*BB+b)*LLn + (LLn-1-l))*DI + d0;
  size_t i2 = ((size_t)(2*BB+b)*LLn + l)*DI + d0;
  size_t i3 = ((size_t)(3*BB+b)*LLn + l)*DI + d0;
  float4 a = *(const float4*)&y[i0], bb4 = *(const float4*)&y[i1];
  float4 c = *(const float4*)&y[i2], dd = *(const float4*)&y[i3];
  size_t zi = ((size_t)b*LLn + l)*DI + d0;
  float4 zv = *(const float4*)&ws[O_Z + zi];
  float4 g;
  g.x = (a.x+bb4.x+c.x+dd.x) * (zv.x*sigf(zv.x));
  g.y = (a.y+bb4.y+c.y+dd.y) * (zv.y*sigf(zv.y));
  g.z = (a.z+bb4.z+c.z+dd.z) * (zv.z*sigf(zv.z));
  g.w = (a.w+bb4.w+c.w+dd.w) * (zv.w*sigf(zv.w));
  *(float4*)&ws[O_Z + zi] = g;
}

// K10: partial spatial mean/max of gf per (b, 128-row segment)
__global__ void k_redmm(float* __restrict__ ws){
  int b = blockIdx.x >> 5, seg = blockIdx.x & 31, c = threadIdx.x; // 128 threads
  const float* gf = ws + O_GF;
  float sm = 0.f, mx = -3e38f;
  size_t base = ((size_t)b*LLn + (size_t)seg*128)*CC + c;
  for(int i=0;i<128;i++){ float v = gf[base + (size_t)i*CC]; sm += v; mx = fmaxf(mx, v); }
  ws[O_PART + ((size_t)b*32 + seg)*CC + c] = sm;
  ws[O_PART + (size_t)BB*32*CC + ((size_t)b*32 + seg)*CC + c] = mx;
}

// K11: channel attention MLP -> sig[b,c]
__global__ void k_catt(float* __restrict__ ws){
  __shared__ float vm[CC], vx[CC], hm[32], hx[32];
  int b = blockIdx.x, c = threadIdx.x;      // 128 threads
  float sm = 0.f, mx = -3e38f;
  for(int seg=0;seg<32;seg++){
    sm += ws[O_PART + ((size_t)b*32+seg)*CC + c];
    mx = fmaxf(mx, ws[O_PART + (size_t)BB*32*CC + ((size_t)b*32+seg)*CC + c]);
  }
  vm[c] = sm * (1.f/(float)LLn); vx[c] = mx;
  __syncthreads();
  if(c < 32){
    float am = 0.f, ax = 0.f;
    for(int k=0;k<CC;k++){ float w1 = ws[OW_CAW1 + c*CC + k]; am += vm[k]*w1; ax += vx[k]*w1; }
    hm[c] = fmaxf(am, 0.f); hx[c] = fmaxf(ax, 0.f);
  }
  __syncthreads();
  float om = 0.f, ox = 0.f;
  for(int k=0;k<32;k++){ float w2 = ws[OW_CAW2 + c*32 + k]; om += hm[k]*w2; ox += hx[k]*w2; }
  ws[O_SIG + (size_t)b*CC + c] = sigf(om + ox);
}

// K12: f4 = gf^2*sig; out0 = dwconv3x3(f4) + dw_b + f4  (f32)
__global__ void k_final(float* __restrict__ ws, float* __restrict__ outf){
  int t = blockIdx.x*256 + threadIdx.x;     // B*L*C/4 = 524288
  int c4 = t & 31, l = (t>>5)&4095, b = t>>17;
  int h = l>>6, w = l&63;
  const float* gf = ws + O_GF;
  float4 sg = *(const float4*)&ws[O_SIG + (size_t)b*CC + c4*4];
  size_t rb = ((size_t)b*LLn)*CC;
  float4 gc = *(const float4*)&gf[rb + (size_t)l*CC + c4*4];
  float4 fc = make_float4(gc.x*gc.x*sg.x, gc.y*gc.y*sg.y, gc.z*gc.z*sg.z, gc.w*gc.w*sg.w);
  float4 acc = *(const float4*)&ws[OW_DWB + c4*4];
  float wv[4][9];
#pragma unroll
  for(int j=0;j<4;j++)
#pragma unroll
    for(int q=0;q<9;q++) wv[j][q] = ws[OW_DWW + (c4*4+j)*9 + q];
#pragma unroll
  for(int kh=0;kh<3;kh++){
    int hh = h + kh - 1; if((unsigned)hh >= 64u) continue;
#pragma unroll
    for(int kw=0;kw<3;kw++){
      int wn = w + kw - 1; if((unsigned)wn >= 64u) continue;
      float4 g = *(const float4*)&gf[rb + (size_t)(hh*64+wn)*CC + c4*4];
      int q = kh*3+kw;
      acc.x += wv[0][q]*g.x*g.x*sg.x;
      acc.y += wv[1][q]*g.y*g.y*sg.y;
      acc.z += wv[2][q]*g.z*g.z*sg.z;
      acc.w += wv[3][q]*g.w*g.w*sg.w;
    }
  }
  float4 o = make_float4(acc.x+fc.x, acc.y+fc.y, acc.z+fc.z, acc.w+fc.w);
  size_t ob = ((size_t)b*LLn + l)*CC + c4*4;
  *(float4*)&outf[ob] = o;                  // output 0 (f32)
}

extern "C" void kernel_launch(void* const* d_in, const int* in_sizes, int n_in,
                              void* d_out, int out_size, void* d_ws, size_t ws_size,
                              hipStream_t stream){
  (void)in_sizes; (void)n_in; (void)out_size;
  if(ws_size < WS_END*sizeof(float)) return;
  float* ws = (float*)d_ws;
  float* outf = (float*)d_out;              // f32 outputs (reference returns float32)
  const void* I1 = d_in[0]; const void* FRES = d_in[1];
  const void* I2 = d_in[2]; const void* FUS  = d_in[3];
  const void* LN1RAW = d_in[4];

  Srcs sr;
  for(int i=0;i<22;i++) sr.p[i] = d_in[4+i];
  k_wcvt<<<(NW_RAW+255)/256, 256, 0, stream>>>(sr, ws);
  k_fuse<<<4096, 256, 0, stream>>>(FUS, FRES, LN1RAW, ws, outf);
  k_meanmax<<<8192, 256, 0, stream>>>(I1, I2, LN1RAW, ws);
  k_spconv<<<128, 256, 0, stream>>>(ws);
  k_escale<<<8192, 256, 0, stream>>>(I1, I2, LN1RAW, ws);
  k_gemm<<<dim3(8,256), 256, 0, stream>>>(ws+O_XF, ws+OW_IPW, nullptr, 128, 512, 1, ws+O_U, ws+O_Z);
  k_gemm<<<dim3(4,256), 256, 0, stream>>>(ws+O_E1, ws+OW_IP1W, ws+O_U+2*BLD, 128, 256, 0, nullptr, nullptr);
  k_gemm<<<dim3(4,256), 256, 0, stream>>>(ws+O_E2, ws+OW_IP2W, ws+O_U+3*BLD, 128, 256, 0, nullptr, nullptr);
  k_convsilu<<<16384, 256, 0, stream>>>(ws);
  k_xproj<<<4096, 256, 0, stream>>>(ws);
  k_scan_seq<<<SS*BB, 256, 0, stream>>>(ws);
  k_gate<<<4096, 256, 0, stream>>>(ws);
  k_gemm<<<dim3(2,256), 256, 0, stream>>>(ws+O_Z, ws+OW_OUTW, ws+O_GF, 256, 128, 0, nullptr, nullptr);
  k_redmm<<<128, 128, 0, stream>>>(ws);
  k_catt<<<4, 128, 0, stream>>>(ws);
  k_final<<<2048, 256, 0, stream>>>(ws, outf);
}

// Round 5
// 450.380 us; speedup vs baseline: 4.0015x; 4.0015x over previous
//
#include <hip/hip_runtime.h>

#define DEVI __device__ __forceinline__

static constexpr int BB=4, CC=128, LLn=4096, DI=256, NS=16, RR=8, SS=4;
static constexpr int PP = RR + 2*NS;            // 40
static constexpr int CT = 64, NCH = LLn/CT;     // scan chunking: 64 chunks of 64
static constexpr size_t BLC  = (size_t)BB*LLn*CC;    // 2,097,152
static constexpr size_t BLD  = (size_t)BB*LLn*DI;    // 4,194,304
static constexpr size_t SBLD = (size_t)SS*BLD;
static constexpr size_t SBLP = (size_t)SS*BB*LLn*PP;

// ---- weight offsets inside ws (floats), padded to multiples of 4 ----
static constexpr int OW_LN1W=0, OW_LN1B=128, OW_LN2W=256, OW_LN2B=384, OW_LN3W=512, OW_LN3B=640,
 OW_SPW=768, OW_CAW1=820, OW_CAW2=4916, OW_DWW=9012, OW_DWB=10164, OW_IPW=10292,
 OW_IP1W=75828, OW_IP2W=108596, OW_CVW=141364, OW_CVB=145460, OW_XPW=146484,
 OW_DTW=187444, OW_DTB=195636, OW_ALOG=196660, OW_DSK=213044, OW_OUTW=214068;
static constexpr int NW_RAW = 246836;   // last tensor end
static constexpr int NW_END = 246848;   // padded

__constant__ int c_woff[22] = {OW_LN1W,OW_LN1B,OW_LN2W,OW_LN2B,OW_LN3W,OW_LN3B,OW_SPW,OW_CAW1,
 OW_CAW2,OW_DWW,OW_DWB,OW_IPW,OW_IP1W,OW_IP2W,OW_CVW,OW_CVB,OW_XPW,OW_DTW,OW_DTB,OW_ALOG,
 OW_DSK,OW_OUTW};
__constant__ int c_wsz[22]  = {128,128,128,128,128,128,50,4096,4096,1152,128,65536,32768,32768,
 4096,1024,40960,8192,1024,16384,1024,32768};

// ---- workspace layout (float offsets) ----
static constexpr size_t O_XF   = NW_END;
static constexpr size_t O_E1   = O_XF + BLC;
static constexpr size_t O_E2   = O_E1 + BLC;
static constexpr size_t O_Z    = O_E2 + BLC;          // later reused for gated g
static constexpr size_t O_U    = O_Z + BLD;           // u streams; later reused for y
static constexpr size_t O_UC   = O_U + SBLD;
static constexpr size_t O_PROJ = O_UC + SBLD;
static constexpr size_t O_SDT  = O_PROJ + SBLP;
static constexpr size_t O_H    = O_SDT + (size_t)SS*BB*NCH*DI;
static constexpr size_t O_M    = O_H + (size_t)SS*BB*NCH*DI*NS;
static constexpr size_t O_S    = O_M + 2*(size_t)BB*2*LLn;
static constexpr size_t O_GF   = O_S + 2*(size_t)BB*LLn;
static constexpr size_t O_PART = O_GF + BLC;
static constexpr size_t O_SIG  = O_PART + 2*(size_t)BB*32*CC;
static constexpr size_t WS_END = O_SIG + (size_t)BB*CC;

// ---- helpers ----
DEVI float bfu2f(unsigned short s){ union{unsigned u; float f;} c; c.u = ((unsigned)s)<<16; return c.f; }
DEVI bool bfmode(const void* ln1w){ return *(const unsigned*)ln1w == 0x3F803F80u; }
DEVI float2 ldin2(const void* p, int i, bool isbf){
  if(isbf){ unsigned v = *(const unsigned*)((const unsigned short*)p + i);
    return make_float2(bfu2f((unsigned short)(v & 0xFFFFu)), bfu2f((unsigned short)(v >> 16))); }
  const float* f = (const float*)p + i; return make_float2(f[0], f[1]);
}
DEVI float wsum(float v){
#pragma unroll
  for(int o=32;o;o>>=1) v += __shfl_xor(v,o,64);
  return v; }
DEVI float wmaxr(float v){
#pragma unroll
  for(int o=32;o;o>>=1) v = fmaxf(v, __shfl_xor(v,o,64));
  return v; }
DEVI float sigf(float x){ return 1.f/(1.f+__expf(-x)); }
// layernorm over 128 channels held as 2 values/lane across one 64-lane wave
DEVI float2 ln_wave(float2 x, const float* Wf, int ow, int ob, int lane){
  float mu = wsum(x.x + x.y) * (1.f/(float)CC);
  float dx = x.x - mu, dy = x.y - mu;
  float var = wsum(dx*dx + dy*dy) * (1.f/(float)CC);
  float rs = rsqrtf(var + 1e-5f);
  int c = 2*lane;
  return make_float2(dx*rs*Wf[ow+c] + Wf[ob+c], dy*rs*Wf[ow+c+1] + Wf[ob+c+1]);
}

struct Srcs { const void* p[22]; };

// K0: convert all weight tensors to f32 workspace
__global__ void k_wcvt(Srcs s, float* __restrict__ ws){
  bool isbf = bfmode(s.p[0]);
  int idx = blockIdx.x*256 + threadIdx.x;
  if(idx >= NW_RAW) return;
  int t = 0;
  while(t < 21 && idx >= c_woff[t+1]) t++;
  int j = idx - c_woff[t];
  if(j >= c_wsz[t]) return;  // padding gap
  float v = isbf ? bfu2f(((const unsigned short*)s.p[t])[j]) : ((const float*)s.p[t])[j];
  ws[idx] = v;
}

// K1: fusion_resi = fusion + fusion_resi -> out1(f32); xf = ln1(ln1(fr))
__global__ void k_fuse(const void* fus, const void* fres, const void* ln1raw,
                       float* __restrict__ ws, float* __restrict__ outf){
  bool isbf = bfmode(ln1raw);
  int lane = threadIdx.x & 63, wv = threadIdx.x >> 6;
  int row = blockIdx.x*4 + wv;              // 16384 rows
  int base = row*CC;
  float2 a = ldin2(fus, base+2*lane, isbf);
  float2 b = ldin2(fres, base+2*lane, isbf);
  float2 fr = make_float2(a.x+b.x, a.y+b.y);
  *(float2*)(outf + BLC + base + 2*lane) = fr;      // output 1 = fusion_resi (f32)
  float2 y = ln_wave(fr, ws, OW_LN1W, OW_LN1B, lane);
  y = ln_wave(y, ws, OW_LN1W, OW_LN1B, lane);
  *(float2*)(ws + O_XF + base + 2*lane) = y;
}

// K2a: per-pixel channel mean/max of I1 (ten=0) and I2 (ten=1)
__global__ void k_meanmax(const void* I1, const void* I2, const void* ln1raw, float* __restrict__ ws){
  bool isbf = bfmode(ln1raw);
  int lane = threadIdx.x & 63, wv = threadIdx.x >> 6;
  int g = blockIdx.x*4 + wv;                // 32768 waves
  int ten = g & 1, row = g >> 1;
  const void* src = ten ? I2 : I1;
  float2 x = ldin2(src, row*CC + 2*lane, isbf);
  float sm = wsum(x.x + x.y) * (1.f/(float)CC);
  float mx = wmaxr(fmaxf(x.x, x.y));
  if(lane == 0){
    int b = row >> 12, l = row & 4095;
    float* mt = ws + O_M + (size_t)ten*(BB*2*LLn);
    mt[(size_t)b*2*LLn + l] = sm;
    mt[(size_t)b*2*LLn + LLn + l] = mx;
  }
}

// K2b: 5x5 conv (2ch->1) + sigmoid -> s1,s2
__global__ void k_spconv(float* __restrict__ ws){
  int idx = blockIdx.x*256 + threadIdx.x;   // 32768
  int ten = idx >> 14, b = (idx>>12)&3, l = idx & 4095;
  int h = l >> 6, w = l & 63;
  const float* mt = ws + O_M + (size_t)ten*(BB*2*LLn) + (size_t)b*2*LLn;
  float acc = 0.f;
  for(int ci=0; ci<2; ci++)
    for(int kh=0; kh<5; kh++){
      int hh = h + kh - 2; if((unsigned)hh >= 64u) continue;
      for(int kw=0; kw<5; kw++){
        int wn = w + kw - 2; if((unsigned)wn >= 64u) continue;
        acc += mt[(size_t)ci*LLn + hh*64 + wn] * ws[OW_SPW + ci*25 + kh*5 + kw];
      }
    }
  ws[O_S + (size_t)ten*(BB*LLn) + (size_t)b*LLn + l] = sigf(acc);
}

// K2c: e1 = ln2(ln2(I2*s2)), e2 = ln3(ln3(I1*s1))
__global__ void k_escale(const void* I1, const void* I2, const void* ln1raw, float* __restrict__ ws){
  bool isbf = bfmode(ln1raw);
  int lane = threadIdx.x & 63, wv = threadIdx.x >> 6;
  int g = blockIdx.x*4 + wv;
  int ten = g & 1, row = g >> 1;            // ten0: e1 from I2; ten1: e2 from I1
  const void* src = ten ? I1 : I2;
  float sc = ws[O_S + (ten ? 0 : (size_t)BB*LLn) + row];
  float2 x = ldin2(src, row*CC + 2*lane, isbf);
  x.x *= sc; x.y *= sc;
  int ow = ten ? OW_LN3W : OW_LN2W, ob = ten ? OW_LN3B : OW_LN2B;
  float2 y = ln_wave(x, ws, ow, ob, lane);
  y = ln_wave(y, ws, ow, ob, lane);
  float* dst = ws + (ten ? O_E2 : O_E1);
  *(float2*)(dst + row*CC + 2*lane) = y;
}

// K3: f32 GEMM  out[m,n] = sum_k A[m,k]*Wt[n,k]; 64x64 tile, transposed LDS
__global__ __launch_bounds__(256) void k_gemm(const float* __restrict__ A, const float* __restrict__ Wt,
    float* __restrict__ out, int Kd, int N, int mode, float* __restrict__ u, float* __restrict__ z){
  __shared__ float As[64][68];
  __shared__ float Bs[64][68];
  const int tx = threadIdx.x & 15, ty = threadIdx.x >> 4;
  const int n0 = blockIdx.x * 64, m0 = blockIdx.y * 64;
  float acc[4][4] = {};
  const int nk = Kd >> 6;
  for(int kt=0; kt<nk; kt++){
#pragma unroll
    for(int i=0;i<16;i++){
      int idx = i*256 + threadIdx.x; int r = idx>>6, c = idx&63;
      As[c][r] = A[(size_t)(m0+r)*Kd + kt*64 + c];
      Bs[c][r] = Wt[(size_t)(n0+r)*Kd + kt*64 + c];
    }
    __syncthreads();
#pragma unroll 8
    for(int k=0;k<64;k++){
      float4 a4 = *(const float4*)&As[k][ty*4];
      float4 b4 = *(const float4*)&Bs[k][tx*4];
      float av[4] = {a4.x,a4.y,a4.z,a4.w};
      float bv[4] = {b4.x,b4.y,b4.z,b4.w};
#pragma unroll
      for(int i=0;i<4;i++)
#pragma unroll
        for(int j=0;j<4;j++) acc[i][j] += av[i]*bv[j];
    }
    __syncthreads();
  }
#pragma unroll
  for(int i=0;i<4;i++){
    int m = m0 + ty*4 + i;
    float4 v = make_float4(acc[i][0],acc[i][1],acc[i][2],acc[i][3]);
    int n = n0 + tx*4;
    if(mode == 0){
      *(float4*)&out[(size_t)m*N + n] = v;
    } else {  // in-proj split: u0, reversed u1, z
      int b = m >> 12, l = m & (LLn-1);
      if(n < DI){
        *(float4*)&u[((size_t)b*LLn + l)*DI + n] = v;
        *(float4*)&u[((size_t)(BB + b)*LLn + (LLn-1-l))*DI + n] = v;
      } else {
        *(float4*)&z[((size_t)b*LLn + l)*DI + (n-DI)] = v;
      }
    }
  }
}

// K4: causal depthwise conv (K=4) + bias + SiLU
__global__ void k_convsilu(float* __restrict__ ws){
  int t = blockIdx.x*256 + threadIdx.x;     // SBLD/4
  int d4 = t & 63, l = (t>>6)&4095, sb = t>>18, s = sb>>2;
  int d0 = d4*4;
  const float* wp = ws + OW_CVW + ((size_t)s*DI + d0)*4;
  float wv[16];
#pragma unroll
  for(int q=0;q<16;q++) wv[q] = wp[q];
  float4 acc = *(const float4*)&ws[OW_CVB + s*DI + d0];
  size_t rb = ((size_t)sb*LLn)*DI;
#pragma unroll
  for(int k=0;k<4;k++){
    int lk = l - 3 + k;
    if(lk >= 0){
      float4 uv = *(const float4*)&ws[O_U + rb + (size_t)lk*DI + d0];
      acc.x += wv[0*4+k]*uv.x; acc.y += wv[1*4+k]*uv.y;
      acc.z += wv[2*4+k]*uv.z; acc.w += wv[3*4+k]*uv.w;
    }
  }
  acc.x *= sigf(acc.x); acc.y *= sigf(acc.y); acc.z *= sigf(acc.z); acc.w *= sigf(acc.w);
  *(float4*)&ws[O_UC + rb + (size_t)l*DI + d0] = acc;
}

// K5: proj[row,p] = sum_d uc[row,d]*xproj_w[s,p,d]
__global__ __launch_bounds__(256) void k_xproj(float* __restrict__ ws){
  __shared__ float ucl[16][260];
  __shared__ float wl[PP][260];
  int r0 = blockIdx.x * 16;                 // rows of 65536
  int s = r0 >> 14;
#pragma unroll
  for(int i=0;i<4;i++){
    int e4 = i*256 + threadIdx.x; int r = e4>>6, c4 = e4&63;
    *(float4*)&ucl[r][c4*4] = *(const float4*)&ws[O_UC + (size_t)(r0+r)*DI + c4*4];
  }
#pragma unroll
  for(int i=0;i<10;i++){
    int e4 = i*256 + threadIdx.x; int r = e4>>6, c4 = e4&63;
    *(float4*)&wl[r][c4*4] = *(const float4*)&ws[OW_XPW + ((size_t)s*PP + r)*DI + c4*4];
  }
  __syncthreads();
  int r = threadIdx.x & 15, ps = threadIdx.x >> 4;
  for(int pp=0; pp<3; pp++){
    int p = ps + pp*16;
    if(p < PP){
      float4 acc = make_float4(0,0,0,0);
#pragma unroll 8
      for(int c4=0;c4<64;c4++){
        float4 a = *(const float4*)&ucl[r][c4*4];
        float4 b = *(const float4*)&wl[p][c4*4];
        acc.x += a.x*b.x; acc.y += a.y*b.y; acc.z += a.z*b.z; acc.w += a.w*b.w;
      }
      ws[O_PROJ + (size_t)(r0+r)*PP + p] = acc.x+acc.y+acc.z+acc.w;
    }
  }
}

// K6/K8: chunk-parallel selective scan.
// PH3=false: local scan (h0=0) -> Hend, Sdt.  PH3=true: re-run with h_in, emit y.
template<bool PH3>
__global__ __launch_bounds__(256) void k_scan(float* __restrict__ ws){
  __shared__ float pl[CT*PP];
  int ch = blockIdx.x & (NCH-1), sb = blockIdx.x >> 6, s = sb >> 2;
  int d = threadIdx.x;
  size_t prow = ((size_t)sb*LLn + (size_t)ch*CT)*PP;
#pragma unroll
  for(int i=0;i<10;i++){ int idx = i*256 + threadIdx.x; pl[idx] = ws[O_PROJ + prow + idx]; }
  __syncthreads();
  float dtw[RR];
#pragma unroll
  for(int r=0;r<RR;r++) dtw[r] = ws[OW_DTW + ((size_t)s*DI + d)*RR + r];
  float dtb = ws[OW_DTB + s*DI + d];
  float an2[NS]; bool fast = true;
#pragma unroll
  for(int n=0;n<NS;n++){
    float a = -__expf(ws[OW_ALOG + ((size_t)s*DI + d)*NS + n]);
    an2[n] = a * 1.44269504f;
    fast = fast && (fabsf(a + (float)(n+1)) < 1e-4f);
  }
  float h[NS];
  size_t hb = (((size_t)sb*NCH + ch)*DI + d)*NS;
  float* H = ws + O_H;
  if(PH3){
#pragma unroll
    for(int q=0;q<4;q++){ float4 v = *(const float4*)&H[hb + q*4];
      h[q*4]=v.x; h[q*4+1]=v.y; h[q*4+2]=v.z; h[q*4+3]=v.w; }
  } else {
#pragma unroll
    for(int n=0;n<NS;n++) h[n] = 0.f;
  }
  float dsk = PH3 ? ws[OW_DSK + s*DI + d] : 0.f;
  float sdt = 0.f;
  size_t ub = ((size_t)sb*LLn + (size_t)ch*CT)*DI + d;
  if(fast){
    for(int ll=0; ll<CT; ll++){
      const float* pr = &pl[ll*PP];
      float x = dtb;
#pragma unroll
      for(int r=0;r<RR;r++) x += pr[r]*dtw[r];
      float dt = (x > 15.f) ? x : __logf(1.f + __expf(x));
      float ut = ws[O_UC + ub + (size_t)ll*DI];
      float du = dt*ut;
      float e = __expf(-dt), da = e;
      if(PH3){
        float y = 0.f;
#pragma unroll
        for(int n=0;n<NS;n++){ h[n] = h[n]*da + du*pr[RR+n]; y += h[n]*pr[RR+NS+n]; da *= e; }
        ws[O_U + ub + (size_t)ll*DI] = y + ut*dsk;
      } else {
#pragma unroll
        for(int n=0;n<NS;n++){ h[n] = h[n]*da + du*pr[RR+n]; da *= e; }
        sdt += dt;
      }
    }
  } else {
    for(int ll=0; ll<CT; ll++){
      const float* pr = &pl[ll*PP];
      float x = dtb;
#pragma unroll
      for(int r=0;r<RR;r++) x += pr[r]*dtw[r];
      float dt = (x > 15.f) ? x : __logf(1.f + __expf(x));
      float ut = ws[O_UC + ub + (size_t)ll*DI];
      float du = dt*ut;
      if(PH3){
        float y = 0.f;
#pragma unroll
        for(int n=0;n<NS;n++){ float da = exp2f(an2[n]*dt); h[n] = h[n]*da + du*pr[RR+n]; y += h[n]*pr[RR+NS+n]; }
        ws[O_U + ub + (size_t)ll*DI] = y + ut*dsk;
      } else {
#pragma unroll
        for(int n=0;n<NS;n++){ float da = exp2f(an2[n]*dt); h[n] = h[n]*da + du*pr[RR+n]; }
        sdt += dt;
      }
    }
  }
  if(!PH3){
#pragma unroll
    for(int q=0;q<4;q++){ float4 v = make_float4(h[q*4],h[q*4+1],h[q*4+2],h[q*4+3]);
      *(float4*)&H[hb + q*4] = v; }
    ws[O_SDT + ((size_t)sb*NCH + ch)*DI + d] = sdt;
  }
}

// K7: combine chunk boundary states: H (Hend) -> H (Hin), in place
__global__ void k_scan2(float* __restrict__ ws){
  int t = blockIdx.x*256 + threadIdx.x;     // 65536 = S*B*DI*NS
  int n = t & (NS-1), d = (t>>4) & (DI-1), sb = t >> 12, s = sb >> 2;
  float an2 = -__expf(ws[OW_ALOG + ((size_t)s*DI + d)*NS + n]) * 1.44269504f;
  float hin = 0.f;
  float* H = ws + O_H;
  for(int c=0;c<NCH;c++){
    size_t hi = (((size_t)sb*NCH + c)*DI + d)*NS + n;
    float he = H[hi];
    float sd = ws[O_SDT + ((size_t)sb*NCH + c)*DI + d];
    H[hi] = hin;
    hin = he + exp2f(an2*sd)*hin;
  }
}

// K9: combine 4 streams (stream1 re-reversed) and gate with silu(z); write into z buffer
__global__ void k_gate(float* __restrict__ ws){
  int t = blockIdx.x*256 + threadIdx.x;     // BLD/4
  int d4 = t & 63, l = (t>>6)&4095, b = t>>18;
  int d0 = d4*4;
  const float* y = ws + O_U;
  size_t i0 = ((size_t)(0*BB+b)*LLn + l)*DI + d0;
  size_t i1 = ((size_t)(1*BB+b)*LLn + (LLn-1-l))*DI + d0;
  size_t i2 = ((size_t)(2*BB+b)*LLn + l)*DI + d0;
  size_t i3 = ((size_t)(3*BB+b)*LLn + l)*DI + d0;
  float4 a = *(const float4*)&y[i0], bb4 = *(const float4*)&y[i1];
  float4 c = *(const float4*)&y[i2], dd = *(const float4*)&y[i3];
  size_t zi = ((size_t)b*LLn + l)*DI + d0;
  float4 zv = *(const float4*)&ws[O_Z + zi];
  float4 g;
  g.x = (a.x+bb4.x+c.x+dd.x) * (zv.x*sigf(zv.x));
  g.y = (a.y+bb4.y+c.y+dd.y) * (zv.y*sigf(zv.y));
  g.z = (a.z+bb4.z+c.z+dd.z) * (zv.z*sigf(zv.z));
  g.w = (a.w+bb4.w+c.w+dd.w) * (zv.w*sigf(zv.w));
  *(float4*)&ws[O_Z + zi] = g;
}

// K10: partial spatial mean/max of gf per (b, 128-row segment)
__global__ void k_redmm(float* __restrict__ ws){
  int b = blockIdx.x >> 5, seg = blockIdx.x & 31, c = threadIdx.x; // 128 threads
  const float* gf = ws + O_GF;
  float sm = 0.f, mx = -3e38f;
  size_t base = ((size_t)b*LLn + (size_t)seg*128)*CC + c;
  for(int i=0;i<128;i++){ float v = gf[base + (size_t)i*CC]; sm += v; mx = fmaxf(mx, v); }
  ws[O_PART + ((size_t)b*32 + seg)*CC + c] = sm;
  ws[O_PART + (size_t)BB*32*CC + ((size_t)b*32 + seg)*CC + c] = mx;
}

// K11: channel attention MLP -> sig[b,c]
__global__ void k_catt(float* __restrict__ ws){
  __shared__ float vm[CC], vx[CC], hm[32], hx[32];
  int b = blockIdx.x, c = threadIdx.x;      // 128 threads
  float sm = 0.f, mx = -3e38f;
  for(int seg=0;seg<32;seg++){
    sm += ws[O_PART + ((size_t)b*32+seg)*CC + c];
    mx = fmaxf(mx, ws[O_PART + (size_t)BB*32*CC + ((size_t)b*32+seg)*CC + c]);
  }
  vm[c] = sm * (1.f/(float)LLn); vx[c] = mx;
  __syncthreads();
  if(c < 32){
    float am = 0.f, ax = 0.f;
    for(int k=0;k<CC;k++){ float w1 = ws[OW_CAW1 + c*CC + k]; am += vm[k]*w1; ax += vx[k]*w1; }
    hm[c] = fmaxf(am, 0.f); hx[c] = fmaxf(ax, 0.f);
  }
  __syncthreads();
  float om = 0.f, ox = 0.f;
  for(int k=0;k<32;k++){ float w2 = ws[OW_CAW2 + c*32 + k]; om += hm[k]*w2; ox += hx[k]*w2; }
  ws[O_SIG + (size_t)b*CC + c] = sigf(om + ox);
}

// K12: f4 = gf^2*sig; out0 = dwconv3x3(f4) + dw_b + f4  (f32)
__global__ void k_final(float* __restrict__ ws, float* __restrict__ outf){
  int t = blockIdx.x*256 + threadIdx.x;     // B*L*C/4 = 524288
  int c4 = t & 31, l = (t>>5)&4095, b = t>>17;
  int h = l>>6, w = l&63;
  const float* gf = ws + O_GF;
  float4 sg = *(const float4*)&ws[O_SIG + (size_t)b*CC + c4*4];
  size_t rb = ((size_t)b*LLn)*CC;
  float4 gc = *(const float4*)&gf[rb + (size_t)l*CC + c4*4];
  float4 fc = make_float4(gc.x*gc.x*sg.x, gc.y*gc.y*sg.y, gc.z*gc.z*sg.z, gc.w*gc.w*sg.w);
  float4 acc = *(const float4*)&ws[OW_DWB + c4*4];
  float wv[4][9];
#pragma unroll
  for(int j=0;j<4;j++)
#pragma unroll
    for(int q=0;q<9;q++) wv[j][q] = ws[OW_DWW + (c4*4+j)*9 + q];
#pragma unroll
  for(int kh=0;kh<3;kh++){
    int hh = h + kh - 1; if((unsigned)hh >= 64u) continue;
#pragma unroll
    for(int kw=0;kw<3;kw++){
      int wn = w + kw - 1; if((unsigned)wn >= 64u) continue;
      float4 g = *(const float4*)&gf[rb + (size_t)(hh*64+wn)*CC + c4*4];
      int q = kh*3+kw;
      acc.x += wv[0][q]*g.x*g.x*sg.x;
      acc.y += wv[1][q]*g.y*g.y*sg.y;
      acc.z += wv[2][q]*g.z*g.z*sg.z;
      acc.w += wv[3][q]*g.w*g.w*sg.w;
    }
  }
  float4 o = make_float4(acc.x+fc.x, acc.y+fc.y, acc.z+fc.z, acc.w+fc.w);
  size_t ob = ((size_t)b*LLn + l)*CC + c4*4;
  *(float4*)&outf[ob] = o;                  // output 0 (f32)
}

extern "C" void kernel_launch(void* const* d_in, const int* in_sizes, int n_in,
                              void* d_out, int out_size, void* d_ws, size_t ws_size,
                              hipStream_t stream){
  (void)in_sizes; (void)n_in; (void)out_size;
  if(ws_size < WS_END*sizeof(float)) return;
  float* ws = (float*)d_ws;
  float* outf = (float*)d_out;              // f32 outputs (reference returns float32)
  const void* I1 = d_in[0]; const void* FRES = d_in[1];
  const void* I2 = d_in[2]; const void* FUS  = d_in[3];
  const void* LN1RAW = d_in[4];

  Srcs sr;
  for(int i=0;i<22;i++) sr.p[i] = d_in[4+i];
  k_wcvt<<<(NW_RAW+255)/256, 256, 0, stream>>>(sr, ws);
  k_fuse<<<4096, 256, 0, stream>>>(FUS, FRES, LN1RAW, ws, outf);
  k_meanmax<<<8192, 256, 0, stream>>>(I1, I2, LN1RAW, ws);
  k_spconv<<<128, 256, 0, stream>>>(ws);
  k_escale<<<8192, 256, 0, stream>>>(I1, I2, LN1RAW, ws);
  k_gemm<<<dim3(8,256), 256, 0, stream>>>(ws+O_XF, ws+OW_IPW, nullptr, 128, 512, 1, ws+O_U, ws+O_Z);
  k_gemm<<<dim3(4,256), 256, 0, stream>>>(ws+O_E1, ws+OW_IP1W, ws+O_U+2*BLD, 128, 256, 0, nullptr, nullptr);
  k_gemm<<<dim3(4,256), 256, 0, stream>>>(ws+O_E2, ws+OW_IP2W, ws+O_U+3*BLD, 128, 256, 0, nullptr, nullptr);
  k_convsilu<<<16384, 256, 0, stream>>>(ws);
  k_xproj<<<4096, 256, 0, stream>>>(ws);
  k_scan<false><<<SS*BB*NCH, 256, 0, stream>>>(ws);
  k_scan2<<<256, 256, 0, stream>>>(ws);
  k_scan<true><<<SS*BB*NCH, 256, 0, stream>>>(ws);
  k_gate<<<4096, 256, 0, stream>>>(ws);
  k_gemm<<<dim3(2,256), 256, 0, stream>>>(ws+O_Z, ws+OW_OUTW, ws+O_GF, 256, 128, 0, nullptr, nullptr);
  k_redmm<<<128, 128, 0, stream>>>(ws);
  k_catt<<<4, 128, 0, stream>>>(ws);
  k_final<<<2048, 256, 0, stream>>>(ws, outf);
}

// Round 6
// 334.168 us; speedup vs baseline: 5.3931x; 1.3478x over previous
//
#include <hip/hip_runtime.h>

#define DEVI __device__ __forceinline__

static constexpr int BB=4, CC=128, LLn=4096, DI=256, NS=16, RR=8, SS=4;
static constexpr int PP = RR + 2*NS;            // 40
static constexpr int CT = 64, NCH = LLn/CT;     // scan chunking: 64 chunks of 64
static constexpr size_t BLC  = (size_t)BB*LLn*CC;    // 2,097,152
static constexpr size_t BLD  = (size_t)BB*LLn*DI;    // 4,194,304
static constexpr size_t SBLD = (size_t)SS*BLD;
static constexpr size_t SBLP = (size_t)SS*BB*LLn*PP;

// ---- weight offsets inside ws (floats), padded to multiples of 4 ----
static constexpr int OW_LN1W=0, OW_LN1B=128, OW_LN2W=256, OW_LN2B=384, OW_LN3W=512, OW_LN3B=640,
 OW_SPW=768, OW_CAW1=820, OW_CAW2=4916, OW_DWW=9012, OW_DWB=10164, OW_IPW=10292,
 OW_IP1W=75828, OW_IP2W=108596, OW_CVW=141364, OW_CVB=145460, OW_XPW=146484,
 OW_DTW=187444, OW_DTB=195636, OW_ALOG=196660, OW_DSK=213044, OW_OUTW=214068;
static constexpr int NW_RAW = 246836;   // last tensor end
static constexpr int NW_END = 246848;   // padded

__constant__ int c_woff[22] = {OW_LN1W,OW_LN1B,OW_LN2W,OW_LN2B,OW_LN3W,OW_LN3B,OW_SPW,OW_CAW1,
 OW_CAW2,OW_DWW,OW_DWB,OW_IPW,OW_IP1W,OW_IP2W,OW_CVW,OW_CVB,OW_XPW,OW_DTW,OW_DTB,OW_ALOG,
 OW_DSK,OW_OUTW};
__constant__ int c_wsz[22]  = {128,128,128,128,128,128,50,4096,4096,1152,128,65536,32768,32768,
 4096,1024,40960,8192,1024,16384,1024,32768};

// ---- workspace layout (float offsets) ----
static constexpr size_t O_XF   = NW_END;              // (now unused, kept for layout stability)
static constexpr size_t O_E1   = O_XF + BLC;          // (unused)
static constexpr size_t O_E2   = O_E1 + BLC;          // (unused)
static constexpr size_t O_Z    = O_E2 + BLC;          // z from in-proj (f32)
static constexpr size_t O_U    = O_Z + BLD;           // u streams; later reused for y
static constexpr size_t O_UC   = O_U + SBLD;
static constexpr size_t O_PROJ = O_UC + SBLD;
static constexpr size_t O_SDT  = O_PROJ + SBLP;
static constexpr size_t O_H    = O_SDT + (size_t)SS*BB*NCH*DI;   // scan state; ALSO aliased:
  // bf16 XBF [0,BLC) shorts, E1BF [BLC,2BLC), E2BF [2BLC,3BLC)  (dead before scan writes H)
  // bf16 GBF [0,BLD) shorts (written after scan, H dead)
static constexpr size_t O_M    = O_H + (size_t)SS*BB*NCH*DI*NS;
static constexpr size_t O_S    = O_M + 2*(size_t)BB*2*LLn;
static constexpr size_t O_GF   = O_S + 2*(size_t)BB*LLn;   // aliased: bf16 in-proj weights (dead before out-proj writes GF)
static constexpr size_t O_PART = O_GF + BLC;               // aliased: bf16 out_w (dead before redmm writes PART)
static constexpr size_t O_SIG  = O_PART + 2*(size_t)BB*32*CC;
static constexpr size_t WS_END = O_SIG + (size_t)BB*CC;

typedef __attribute__((ext_vector_type(8))) short short8v;   // 8 bf16 (4 VGPR)
typedef __attribute__((ext_vector_type(4))) float f32x4;     // MFMA acc

// ---- helpers ----
DEVI float bfu2f(unsigned short s){ union{unsigned u; float f;} c; c.u = ((unsigned)s)<<16; return c.f; }
DEVI unsigned short f2bfu(float f){ union{float f; unsigned u;} c; c.f=f;
  unsigned r = c.u + 0x7FFFu + ((c.u>>16)&1u); return (unsigned short)(r>>16); }
DEVI bool bfmode(const void* ln1w){ return *(const unsigned*)ln1w == 0x3F803F80u; }
DEVI float2 ldin2(const void* p, int i, bool isbf){
  if(isbf){ unsigned v = *(const unsigned*)((const unsigned short*)p + i);
    return make_float2(bfu2f((unsigned short)(v & 0xFFFFu)), bfu2f((unsigned short)(v >> 16))); }
  const float* f = (const float*)p + i; return make_float2(f[0], f[1]);
}
DEVI float wsum(float v){
#pragma unroll
  for(int o=32;o;o>>=1) v += __shfl_xor(v,o,64);
  return v; }
DEVI float wmaxr(float v){
#pragma unroll
  for(int o=32;o;o>>=1) v = fmaxf(v, __shfl_xor(v,o,64));
  return v; }
DEVI float sigf(float x){ return 1.f/(1.f+__expf(-x)); }
// layernorm over 128 channels held as 2 values/lane across one 64-lane wave
DEVI float2 ln_wave(float2 x, const float* Wf, int ow, int ob, int lane){
  float mu = wsum(x.x + x.y) * (1.f/(float)CC);
  float dx = x.x - mu, dy = x.y - mu;
  float var = wsum(dx*dx + dy*dy) * (1.f/(float)CC);
  float rs = rsqrtf(var + 1e-5f);
  int c = 2*lane;
  return make_float2(dx*rs*Wf[ow+c] + Wf[ob+c], dy*rs*Wf[ow+c+1] + Wf[ob+c+1]);
}

struct Srcs { const void* p[22]; };

// K0: convert all weight tensors to f32 workspace (+ bf16 copies of GEMM weights)
__global__ void k_wcvt(Srcs s, float* __restrict__ ws,
                       unsigned short* __restrict__ wip, unsigned short* __restrict__ wob){
  bool isbf = bfmode(s.p[0]);
  int idx = blockIdx.x*256 + threadIdx.x;
  if(idx >= NW_RAW) return;
  int t = 0;
  while(t < 21 && idx >= c_woff[t+1]) t++;
  int j = idx - c_woff[t];
  if(j >= c_wsz[t]) return;  // padding gap
  float v = isbf ? bfu2f(((const unsigned short*)s.p[t])[j]) : ((const float*)s.p[t])[j];
  ws[idx] = v;
  if(t==11)      wip[j]         = f2bfu(v);   // in_proj_w
  else if(t==12) wip[65536+j]   = f2bfu(v);   // in_proj1_w
  else if(t==13) wip[98304+j]   = f2bfu(v);   // in_proj2_w
  else if(t==21) wob[j]         = f2bfu(v);   // out_w
}

// K1: fusion_resi = fusion + fusion_resi -> out1(f32); xf(bf16) = ln1(ln1(fr))
__global__ void k_fuse(const void* fus, const void* fres, const void* ln1raw,
                       float* __restrict__ ws, float* __restrict__ outf,
                       unsigned short* __restrict__ xbf){
  bool isbf = bfmode(ln1raw);
  int lane = threadIdx.x & 63, wv = threadIdx.x >> 6;
  int row = blockIdx.x*4 + wv;              // 16384 rows
  int base = row*CC;
  float2 a = ldin2(fus, base+2*lane, isbf);
  float2 b = ldin2(fres, base+2*lane, isbf);
  float2 fr = make_float2(a.x+b.x, a.y+b.y);
  *(float2*)(outf + BLC + base + 2*lane) = fr;      // output 1 = fusion_resi (f32)
  float2 y = ln_wave(fr, ws, OW_LN1W, OW_LN1B, lane);
  y = ln_wave(y, ws, OW_LN1W, OW_LN1B, lane);
  unsigned pk = (unsigned)f2bfu(y.x) | ((unsigned)f2bfu(y.y)<<16);
  *(unsigned*)&xbf[base + 2*lane] = pk;
}

// K2a: per-pixel channel mean/max of I1 (ten=0) and I2 (ten=1)
__global__ void k_meanmax(const void* I1, const void* I2, const void* ln1raw, float* __restrict__ ws){
  bool isbf = bfmode(ln1raw);
  int lane = threadIdx.x & 63, wv = threadIdx.x >> 6;
  int g = blockIdx.x*4 + wv;                // 32768 waves
  int ten = g & 1, row = g >> 1;
  const void* src = ten ? I2 : I1;
  float2 x = ldin2(src, row*CC + 2*lane, isbf);
  float sm = wsum(x.x + x.y) * (1.f/(float)CC);
  float mx = wmaxr(fmaxf(x.x, x.y));
  if(lane == 0){
    int b = row >> 12, l = row & 4095;
    float* mt = ws + O_M + (size_t)ten*(BB*2*LLn);
    mt[(size_t)b*2*LLn + l] = sm;
    mt[(size_t)b*2*LLn + LLn + l] = mx;
  }
}

// K2b: 5x5 conv (2ch->1) + sigmoid -> s1,s2
__global__ void k_spconv(float* __restrict__ ws){
  int idx = blockIdx.x*256 + threadIdx.x;   // 32768
  int ten = idx >> 14, b = (idx>>12)&3, l = idx & 4095;
  int h = l >> 6, w = l & 63;
  const float* mt = ws + O_M + (size_t)ten*(BB*2*LLn) + (size_t)b*2*LLn;
  float acc = 0.f;
  for(int ci=0; ci<2; ci++)
    for(int kh=0; kh<5; kh++){
      int hh = h + kh - 2; if((unsigned)hh >= 64u) continue;
      for(int kw=0; kw<5; kw++){
        int wn = w + kw - 2; if((unsigned)wn >= 64u) continue;
        acc += mt[(size_t)ci*LLn + hh*64 + wn] * ws[OW_SPW + ci*25 + kh*5 + kw];
      }
    }
  ws[O_S + (size_t)ten*(BB*LLn) + (size_t)b*LLn + l] = sigf(acc);
}

// K2c: e1(bf16) = ln2(ln2(I2*s2)), e2(bf16) = ln3(ln3(I1*s1))
__global__ void k_escale(const void* I1, const void* I2, const void* ln1raw,
                         float* __restrict__ ws, unsigned short* __restrict__ xbf){
  bool isbf = bfmode(ln1raw);
  int lane = threadIdx.x & 63, wv = threadIdx.x >> 6;
  int g = blockIdx.x*4 + wv;
  int ten = g & 1, row = g >> 1;            // ten0: e1 from I2; ten1: e2 from I1
  const void* src = ten ? I1 : I2;
  float sc = ws[O_S + (ten ? 0 : (size_t)BB*LLn) + row];
  float2 x = ldin2(src, row*CC + 2*lane, isbf);
  x.x *= sc; x.y *= sc;
  int ow = ten ? OW_LN3W : OW_LN2W, ob = ten ? OW_LN3B : OW_LN2B;
  float2 y = ln_wave(x, ws, ow, ob, lane);
  y = ln_wave(y, ws, ow, ob, lane);
  unsigned short* eb = xbf + (ten ? 2*BLC : BLC);
  unsigned pk = (unsigned)f2bfu(y.x) | ((unsigned)f2bfu(y.y)<<16);
  *(unsigned*)&eb[row*CC + 2*lane] = pk;
}

// K3: bf16 MFMA GEMM  out[m,n] = sum_k A[m,k]*W[n,k].
// 64x64 tile, 4 waves; wave w owns cols [w*16, w*16+16); 16x16x32 MFMA; XOR-swizzled LDS.
__global__ __launch_bounds__(256) void k_gemm_bf(const unsigned short* __restrict__ Abf,
    const unsigned short* __restrict__ Wbf, float* __restrict__ out,
    int Kd, int N, int mode, float* __restrict__ u, float* __restrict__ z){
  __shared__ unsigned short As[64*64];
  __shared__ unsigned short Bs[64*64];
  const int tid = threadIdx.x, lane = tid & 63, w = tid >> 6;
  const int n0 = blockIdx.x*64, m0 = blockIdx.y*64;
  const int g = lane >> 4, rlo = lane & 15;
  f32x4 acc[4];
#pragma unroll
  for(int i=0;i<4;i++) acc[i] = (f32x4){0.f,0.f,0.f,0.f};
  const int nk = Kd >> 6;
  for(int kt=0; kt<nk; kt++){
#pragma unroll
    for(int it=0; it<2; it++){               // stage 64x64 bf16 A and B tiles
      int idx = it*256 + tid, r = idx>>3, c = idx&7;
      uint4 av = *(const uint4*)&Abf[(size_t)(m0+r)*Kd + kt*64 + c*8];
      uint4 bv = *(const uint4*)&Wbf[(size_t)(n0+r)*Kd + kt*64 + c*8];
      int sw = (c*16) ^ ((r&7)<<4);          // bank swizzle (G4)
      *(uint4*)((char*)As + r*128 + sw) = av;
      *(uint4*)((char*)Bs + r*128 + sw) = bv;
    }
    __syncthreads();
#pragma unroll
    for(int ks=0; ks<2; ks++){
      int kb = ks*64 + g*16;
      int brow = w*16 + rlo;
      short8v bf = *(short8v*)((char*)Bs + brow*128 + (kb ^ ((rlo&7)<<4)));
#pragma unroll
      for(int rt=0; rt<4; rt++){
        int arow = rt*16 + rlo;
        short8v af = *(short8v*)((char*)As + arow*128 + (kb ^ ((rlo&7)<<4)));
        acc[rt] = __builtin_amdgcn_mfma_f32_16x16x32_bf16(af, bf, acc[rt], 0, 0, 0);
      }
    }
    __syncthreads();
  }
#pragma unroll
  for(int rt=0; rt<4; rt++){
#pragma unroll
    for(int j=0; j<4; j++){
      int m = m0 + rt*16 + g*4 + j;          // D: row=(lane>>4)*4+reg, col=lane&15 [m89]
      int n = n0 + w*16 + rlo;
      float val = acc[rt][j];
      if(mode == 0){
        out[(size_t)m*N + n] = val;
      } else {  // in-proj split: u0, reversed u1, z
        int b = m >> 12, l = m & (LLn-1);
        if(n < DI){
          u[((size_t)b*LLn + l)*DI + n] = val;
          u[((size_t)(BB + b)*LLn + (LLn-1-l))*DI + n] = val;
        } else {
          z[((size_t)b*LLn + l)*DI + (n-DI)] = val;
        }
      }
    }
  }
}

// K4: causal depthwise conv (K=4) + bias + SiLU
__global__ void k_convsilu(float* __restrict__ ws){
  int t = blockIdx.x*256 + threadIdx.x;     // SBLD/4
  int d4 = t & 63, l = (t>>6)&4095, sb = t>>18, s = sb>>2;
  int d0 = d4*4;
  const float* wp = ws + OW_CVW + ((size_t)s*DI + d0)*4;
  float wv[16];
#pragma unroll
  for(int q=0;q<16;q++) wv[q] = wp[q];
  float4 acc = *(const float4*)&ws[OW_CVB + s*DI + d0];
  size_t rb = ((size_t)sb*LLn)*DI;
#pragma unroll
  for(int k=0;k<4;k++){
    int lk = l - 3 + k;
    if(lk >= 0){
      float4 uv = *(const float4*)&ws[O_U + rb + (size_t)lk*DI + d0];
      acc.x += wv[0*4+k]*uv.x; acc.y += wv[1*4+k]*uv.y;
      acc.z += wv[2*4+k]*uv.z; acc.w += wv[3*4+k]*uv.w;
    }
  }
  acc.x *= sigf(acc.x); acc.y *= sigf(acc.y); acc.z *= sigf(acc.z); acc.w *= sigf(acc.w);
  *(float4*)&ws[O_UC + rb + (size_t)l*DI + d0] = acc;
}

// K5: proj[row,p] = sum_d uc[row,d]*xproj_w[s,p,d]
__global__ __launch_bounds__(256) void k_xproj(float* __restrict__ ws){
  __shared__ float ucl[16][260];
  __shared__ float wl[PP][260];
  int r0 = blockIdx.x * 16;                 // rows of 65536
  int s = r0 >> 14;
#pragma unroll
  for(int i=0;i<4;i++){
    int e4 = i*256 + threadIdx.x; int r = e4>>6, c4 = e4&63;
    *(float4*)&ucl[r][c4*4] = *(const float4*)&ws[O_UC + (size_t)(r0+r)*DI + c4*4];
  }
#pragma unroll
  for(int i=0;i<10;i++){
    int e4 = i*256 + threadIdx.x; int r = e4>>6, c4 = e4&63;
    *(float4*)&wl[r][c4*4] = *(const float4*)&ws[OW_XPW + ((size_t)s*PP + r)*DI + c4*4];
  }
  __syncthreads();
  int r = threadIdx.x & 15, ps = threadIdx.x >> 4;
  for(int pp=0; pp<3; pp++){
    int p = ps + pp*16;
    if(p < PP){
      float4 acc = make_float4(0,0,0,0);
#pragma unroll 8
      for(int c4=0;c4<64;c4++){
        float4 a = *(const float4*)&ucl[r][c4*4];
        float4 b = *(const float4*)&wl[p][c4*4];
        acc.x += a.x*b.x; acc.y += a.y*b.y; acc.z += a.z*b.z; acc.w += a.w*b.w;
      }
      ws[O_PROJ + (size_t)(r0+r)*PP + p] = acc.x+acc.y+acc.z+acc.w;
    }
  }
}

// K6/K8: chunk-parallel selective scan.
// PH3=false: local scan (h0=0) -> Hend, Sdt.  PH3=true: re-run with h_in, emit y.
template<bool PH3>
__global__ __launch_bounds__(256) void k_scan(float* __restrict__ ws){
  __shared__ float pl[CT*PP];
  int ch = blockIdx.x & (NCH-1), sb = blockIdx.x >> 6, s = sb >> 2;
  int d = threadIdx.x;
  size_t prow = ((size_t)sb*LLn + (size_t)ch*CT)*PP;
#pragma unroll
  for(int i=0;i<10;i++){ int idx = i*256 + threadIdx.x; pl[idx] = ws[O_PROJ + prow + idx]; }
  __syncthreads();
  float dtw[RR];
#pragma unroll
  for(int r=0;r<RR;r++) dtw[r] = ws[OW_DTW + ((size_t)s*DI + d)*RR + r];
  float dtb = ws[OW_DTB + s*DI + d];
  float an2[NS]; bool fast = true;
#pragma unroll
  for(int n=0;n<NS;n++){
    float a = -__expf(ws[OW_ALOG + ((size_t)s*DI + d)*NS + n]);
    an2[n] = a * 1.44269504f;
    fast = fast && (fabsf(a + (float)(n+1)) < 1e-4f);
  }
  float h[NS];
  size_t hb = (((size_t)sb*NCH + ch)*DI + d)*NS;
  float* H = ws + O_H;
  if(PH3){
#pragma unroll
    for(int q=0;q<4;q++){ float4 v = *(const float4*)&H[hb + q*4];
      h[q*4]=v.x; h[q*4+1]=v.y; h[q*4+2]=v.z; h[q*4+3]=v.w; }
  } else {
#pragma unroll
    for(int n=0;n<NS;n++) h[n] = 0.f;
  }
  float dsk = PH3 ? ws[OW_DSK + s*DI + d] : 0.f;
  float sdt = 0.f;
  size_t ub = ((size_t)sb*LLn + (size_t)ch*CT)*DI + d;
  if(fast){
    for(int ll=0; ll<CT; ll++){
      const float* pr = &pl[ll*PP];
      float x = dtb;
#pragma unroll
      for(int r=0;r<RR;r++) x += pr[r]*dtw[r];
      float dt = (x > 15.f) ? x : __logf(1.f + __expf(x));
      float ut = ws[O_UC + ub + (size_t)ll*DI];
      float du = dt*ut;
      float e = __expf(-dt), da = e;
      if(PH3){
        float y = 0.f;
#pragma unroll
        for(int n=0;n<NS;n++){ h[n] = h[n]*da + du*pr[RR+n]; y += h[n]*pr[RR+NS+n]; da *= e; }
        ws[O_U + ub + (size_t)ll*DI] = y + ut*dsk;
      } else {
#pragma unroll
        for(int n=0;n<NS;n++){ h[n] = h[n]*da + du*pr[RR+n]; da *= e; }
        sdt += dt;
      }
    }
  } else {
    for(int ll=0; ll<CT; ll++){
      const float* pr = &pl[ll*PP];
      float x = dtb;
#pragma unroll
      for(int r=0;r<RR;r++) x += pr[r]*dtw[r];
      float dt = (x > 15.f) ? x : __logf(1.f + __expf(x));
      float ut = ws[O_UC + ub + (size_t)ll*DI];
      float du = dt*ut;
      if(PH3){
        float y = 0.f;
#pragma unroll
        for(int n=0;n<NS;n++){ float da = exp2f(an2[n]*dt); h[n] = h[n]*da + du*pr[RR+n]; y += h[n]*pr[RR+NS+n]; }
        ws[O_U + ub + (size_t)ll*DI] = y + ut*dsk;
      } else {
#pragma unroll
        for(int n=0;n<NS;n++){ float da = exp2f(an2[n]*dt); h[n] = h[n]*da + du*pr[RR+n]; }
        sdt += dt;
      }
    }
  }
  if(!PH3){
#pragma unroll
    for(int q=0;q<4;q++){ float4 v = make_float4(h[q*4],h[q*4+1],h[q*4+2],h[q*4+3]);
      *(float4*)&H[hb + q*4] = v; }
    ws[O_SDT + ((size_t)sb*NCH + ch)*DI + d] = sdt;
  }
}

// K7: combine chunk boundary states: H (Hend) -> H (Hin), in place
__global__ void k_scan2(float* __restrict__ ws){
  int t = blockIdx.x*256 + threadIdx.x;     // 65536 = S*B*DI*NS
  int n = t & (NS-1), d = (t>>4) & (DI-1), sb = t >> 12, s = sb >> 2;
  float an2 = -__expf(ws[OW_ALOG + ((size_t)s*DI + d)*NS + n]) * 1.44269504f;
  float hin = 0.f;
  float* H = ws + O_H;
  for(int c=0;c<NCH;c++){
    size_t hi = (((size_t)sb*NCH + c)*DI + d)*NS + n;
    float he = H[hi];
    float sd = ws[O_SDT + ((size_t)sb*NCH + c)*DI + d];
    H[hi] = hin;
    hin = he + exp2f(an2*sd)*hin;
  }
}

// K9: combine 4 streams (stream1 re-reversed), gate with silu(z) -> gbf (bf16)
__global__ void k_gate(float* __restrict__ ws, unsigned short* __restrict__ gbf){
  int t = blockIdx.x*256 + threadIdx.x;     // BLD/4
  int d4 = t & 63, l = (t>>6)&4095, b = t>>18;
  int d0 = d4*4;
  const float* y = ws + O_U;
  size_t i0 = ((size_t)(0*BB+b)*LLn + l)*DI + d0;
  size_t i1 = ((size_t)(1*BB+b)*LLn + (LLn-1-l))*DI + d0;
  size_t i2 = ((size_t)(2*BB+b)*LLn + l)*DI + d0;
  size_t i3 = ((size_t)(3*BB+b)*LLn + l)*DI + d0;
  float4 a = *(const float4*)&y[i0], bb4 = *(const float4*)&y[i1];
  float4 c = *(const float4*)&y[i2], dd = *(const float4*)&y[i3];
  size_t zi = ((size_t)b*LLn + l)*DI + d0;
  float4 zv = *(const float4*)&ws[O_Z + zi];
  float4 g;
  g.x = (a.x+bb4.x+c.x+dd.x) * (zv.x*sigf(zv.x));
  g.y = (a.y+bb4.y+c.y+dd.y) * (zv.y*sigf(zv.y));
  g.z = (a.z+bb4.z+c.z+dd.z) * (zv.z*sigf(zv.z));
  g.w = (a.w+bb4.w+c.w+dd.w) * (zv.w*sigf(zv.w));
  uint2 pk;
  pk.x = (unsigned)f2bfu(g.x) | ((unsigned)f2bfu(g.y)<<16);
  pk.y = (unsigned)f2bfu(g.z) | ((unsigned)f2bfu(g.w)<<16);
  *(uint2*)&gbf[zi] = pk;
}

// K10: partial spatial mean/max of gf per (b, 128-row segment)
__global__ void k_redmm(float* __restrict__ ws){
  int b = blockIdx.x >> 5, seg = blockIdx.x & 31, c = threadIdx.x; // 128 threads
  const float* gf = ws + O_GF;
  float sm = 0.f, mx = -3e38f;
  size_t base = ((size_t)b*LLn + (size_t)seg*128)*CC + c;
  for(int i=0;i<128;i++){ float v = gf[base + (size_t)i*CC]; sm += v; mx = fmaxf(mx, v); }
  ws[O_PART + ((size_t)b*32 + seg)*CC + c] = sm;
  ws[O_PART + (size_t)BB*32*CC + ((size_t)b*32 + seg)*CC + c] = mx;
}

// K11: channel attention MLP -> sig[b,c]
__global__ void k_catt(float* __restrict__ ws){
  __shared__ float vm[CC], vx[CC], hm[32], hx[32];
  int b = blockIdx.x, c = threadIdx.x;      // 128 threads
  float sm = 0.f, mx = -3e38f;
  for(int seg=0;seg<32;seg++){
    sm += ws[O_PART + ((size_t)b*32+seg)*CC + c];
    mx = fmaxf(mx, ws[O_PART + (size_t)BB*32*CC + ((size_t)b*32+seg)*CC + c]);
  }
  vm[c] = sm * (1.f/(float)LLn); vx[c] = mx;
  __syncthreads();
  if(c < 32){
    float am = 0.f, ax = 0.f;
    for(int k=0;k<CC;k++){ float w1 = ws[OW_CAW1 + c*CC + k]; am += vm[k]*w1; ax += vx[k]*w1; }
    hm[c] = fmaxf(am, 0.f); hx[c] = fmaxf(ax, 0.f);
  }
  __syncthreads();
  float om = 0.f, ox = 0.f;
  for(int k=0;k<32;k++){ float w2 = ws[OW_CAW2 + c*32 + k]; om += hm[k]*w2; ox += hx[k]*w2; }
  ws[O_SIG + (size_t)b*CC + c] = sigf(om + ox);
}

// K12: f4 = gf^2*sig; out0 = dwconv3x3(f4) + dw_b + f4  (f32)
__global__ void k_final(float* __restrict__ ws, float* __restrict__ outf){
  int t = blockIdx.x*256 + threadIdx.x;     // B*L*C/4 = 524288
  int c4 = t & 31, l = (t>>5)&4095, b = t>>17;
  int h = l>>6, w = l&63;
  const float* gf = ws + O_GF;
  float4 sg = *(const float4*)&ws[O_SIG + (size_t)b*CC + c4*4];
  size_t rb = ((size_t)b*LLn)*CC;
  float4 gc = *(const float4*)&gf[rb + (size_t)l*CC + c4*4];
  float4 fc = make_float4(gc.x*gc.x*sg.x, gc.y*gc.y*sg.y, gc.z*gc.z*sg.z, gc.w*gc.w*sg.w);
  float4 acc = *(const float4*)&ws[OW_DWB + c4*4];
  float wv[4][9];
#pragma unroll
  for(int j=0;j<4;j++)
#pragma unroll
    for(int q=0;q<9;q++) wv[j][q] = ws[OW_DWW + (c4*4+j)*9 + q];
#pragma unroll
  for(int kh=0;kh<3;kh++){
    int hh = h + kh - 1; if((unsigned)hh >= 64u) continue;
#pragma unroll
    for(int kw=0;kw<3;kw++){
      int wn = w + kw - 1; if((unsigned)wn >= 64u) continue;
      float4 g = *(const float4*)&gf[rb + (size_t)(hh*64+wn)*CC + c4*4];
      int q = kh*3+kw;
      acc.x += wv[0][q]*g.x*g.x*sg.x;
      acc.y += wv[1][q]*g.y*g.y*sg.y;
      acc.z += wv[2][q]*g.z*g.z*sg.z;
      acc.w += wv[3][q]*g.w*g.w*sg.w;
    }
  }
  float4 o = make_float4(acc.x+fc.x, acc.y+fc.y, acc.z+fc.z, acc.w+fc.w);
  size_t ob = ((size_t)b*LLn + l)*CC + c4*4;
  *(float4*)&outf[ob] = o;                  // output 0 (f32)
}

extern "C" void kernel_launch(void* const* d_in, const int* in_sizes, int n_in,
                              void* d_out, int out_size, void* d_ws, size_t ws_size,
                              hipStream_t stream){
  (void)in_sizes; (void)n_in; (void)out_size;
  if(ws_size < WS_END*sizeof(float)) return;
  float* ws = (float*)d_ws;
  float* outf = (float*)d_out;              // f32 outputs (reference returns float32)
  const void* I1 = d_in[0]; const void* FRES = d_in[1];
  const void* I2 = d_in[2]; const void* FUS  = d_in[3];
  const void* LN1RAW = d_in[4];

  // bf16 aliases over dead-at-the-time f32 regions
  unsigned short* xbf   = (unsigned short*)(ws + O_H);    // xf [0,BLC), e1 [BLC,2BLC), e2 [2BLC,3BLC)
  unsigned short* gbf   = xbf;                            // gated, after scan (H dead)
  unsigned short* wipbf = (unsigned short*)(ws + O_GF);   // ipw | ip1w | ip2w (bf16)
  unsigned short* wobf  = (unsigned short*)(ws + O_PART); // out_w (bf16)

  Srcs sr;
  for(int i=0;i<22;i++) sr.p[i] = d_in[4+i];
  k_wcvt<<<(NW_RAW+255)/256, 256, 0, stream>>>(sr, ws, wipbf, wobf);
  k_fuse<<<4096, 256, 0, stream>>>(FUS, FRES, LN1RAW, ws, outf, xbf);
  k_meanmax<<<8192, 256, 0, stream>>>(I1, I2, LN1RAW, ws);
  k_spconv<<<128, 256, 0, stream>>>(ws);
  k_escale<<<8192, 256, 0, stream>>>(I1, I2, LN1RAW, ws, xbf);
  // MFMA GEMMs: in-proj (split u0/u1rev/z), e1->u2, e2->u3
  k_gemm_bf<<<dim3(8,256), 256, 0, stream>>>(xbf,         wipbf,       nullptr,        128, 512, 1, ws+O_U, ws+O_Z);
  k_gemm_bf<<<dim3(4,256), 256, 0, stream>>>(xbf+BLC,     wipbf+65536, ws+O_U+2*BLD,   128, 256, 0, nullptr, nullptr);
  k_gemm_bf<<<dim3(4,256), 256, 0, stream>>>(xbf+2*BLC,   wipbf+98304, ws+O_U+3*BLD,   128, 256, 0, nullptr, nullptr);
  k_convsilu<<<16384, 256, 0, stream>>>(ws);
  k_xproj<<<4096, 256, 0, stream>>>(ws);
  k_scan<false><<<SS*BB*NCH, 256, 0, stream>>>(ws);
  k_scan2<<<256, 256, 0, stream>>>(ws);
  k_scan<true><<<SS*BB*NCH, 256, 0, stream>>>(ws);
  k_gate<<<4096, 256, 0, stream>>>(ws, gbf);
  // out-proj: gf = g @ out_w.T  (reads gbf at O_H, writes O_GF over dead wipbf)
  k_gemm_bf<<<dim3(2,256), 256, 0, stream>>>(gbf, wobf, ws+O_GF, 256, 128, 0, nullptr, nullptr);
  k_redmm<<<128, 128, 0, stream>>>(ws);
  k_catt<<<4, 128, 0, stream>>>(ws);
  k_final<<<2048, 256, 0, stream>>>(ws, outf);
}

// Round 7
// 295.415 us; speedup vs baseline: 6.1005x; 1.1312x over previous
//
#include <hip/hip_runtime.h>

#define DEVI __device__ __forceinline__

static constexpr int BB=4, CC=128, LLn=4096, DI=256, NS=16, RR=8, SS=4;
static constexpr int PP = RR + 2*NS;            // 40
static constexpr int CT = 64, NCH = LLn/CT;     // scan chunking: 64 chunks of 64
static constexpr size_t BLC  = (size_t)BB*LLn*CC;    // 2,097,152
static constexpr size_t BLD  = (size_t)BB*LLn*DI;    // 4,194,304
static constexpr size_t SBLD = (size_t)SS*BLD;
static constexpr size_t SBLP = (size_t)SS*BB*LLn*PP;

// ---- weight offsets inside ws (floats), padded to multiples of 4 ----
static constexpr int OW_LN1W=0, OW_LN1B=128, OW_LN2W=256, OW_LN2B=384, OW_LN3W=512, OW_LN3B=640,
 OW_SPW=768, OW_CAW1=820, OW_CAW2=4916, OW_DWW=9012, OW_DWB=10164, OW_IPW=10292,
 OW_IP1W=75828, OW_IP2W=108596, OW_CVW=141364, OW_CVB=145460, OW_XPW=146484,
 OW_DTW=187444, OW_DTB=195636, OW_ALOG=196660, OW_DSK=213044, OW_OUTW=214068;
static constexpr int NW_RAW = 246836;   // last tensor end
static constexpr int NW_END = 246848;   // padded

__constant__ int c_woff[22] = {OW_LN1W,OW_LN1B,OW_LN2W,OW_LN2B,OW_LN3W,OW_LN3B,OW_SPW,OW_CAW1,
 OW_CAW2,OW_DWW,OW_DWB,OW_IPW,OW_IP1W,OW_IP2W,OW_CVW,OW_CVB,OW_XPW,OW_DTW,OW_DTB,OW_ALOG,
 OW_DSK,OW_OUTW};
__constant__ int c_wsz[22]  = {128,128,128,128,128,128,50,4096,4096,1152,128,65536,32768,32768,
 4096,1024,40960,8192,1024,16384,1024,32768};

// ---- workspace layout (float offsets) ----
static constexpr size_t O_XF   = NW_END;              // (unused, layout stability)
static constexpr size_t O_E1   = O_XF + BLC;          // (unused)
static constexpr size_t O_E2   = O_E1 + BLC;          // (unused)
static constexpr size_t O_Z    = O_E2 + BLC;          // z from in-proj (f32)
static constexpr size_t O_U    = O_Z + BLD;           // u streams (u1 not materialized); later y
static constexpr size_t O_UC   = O_U + SBLD;
static constexpr size_t O_PROJ = O_UC + SBLD;
static constexpr size_t O_SDT  = O_PROJ + SBLP;
static constexpr size_t O_H    = O_SDT + (size_t)SS*BB*NCH*DI;   // scan state; ALSO aliased:
  // bf16 XBF [0,BLC) shorts, E1BF [BLC,2BLC), E2BF [2BLC,3BLC)  (dead before scan writes H)
  // bf16 GBF [0,BLD) shorts (written after scan, H dead)
static constexpr size_t O_M    = O_H + (size_t)SS*BB*NCH*DI*NS;
static constexpr size_t O_S    = O_M + 2*(size_t)BB*2*LLn;
static constexpr size_t O_GF   = O_S + 2*(size_t)BB*LLn;   // aliased: bf16 in-proj weights
static constexpr size_t O_PART = O_GF + BLC;               // aliased: bf16 out_w
static constexpr size_t O_SIG  = O_PART + 2*(size_t)BB*32*CC;
static constexpr size_t WS_END = O_SIG + (size_t)BB*CC;

typedef __attribute__((ext_vector_type(8))) short short8v;   // 8 bf16 (4 VGPR)
typedef __attribute__((ext_vector_type(4))) float f32x4;     // MFMA acc

// ---- helpers ----
DEVI float bfu2f(unsigned short s){ union{unsigned u; float f;} c; c.u = ((unsigned)s)<<16; return c.f; }
DEVI unsigned short f2bfu(float f){ union{float f; unsigned u;} c; c.f=f;
  unsigned r = c.u + 0x7FFFu + ((c.u>>16)&1u); return (unsigned short)(r>>16); }
DEVI bool bfmode(const void* ln1w){ return *(const unsigned*)ln1w == 0x3F803F80u; }
DEVI float2 ldin2(const void* p, int i, bool isbf){
  if(isbf){ unsigned v = *(const unsigned*)((const unsigned short*)p + i);
    return make_float2(bfu2f((unsigned short)(v & 0xFFFFu)), bfu2f((unsigned short)(v >> 16))); }
  const float* f = (const float*)p + i; return make_float2(f[0], f[1]);
}
DEVI float wsum(float v){
#pragma unroll
  for(int o=32;o;o>>=1) v += __shfl_xor(v,o,64);
  return v; }
DEVI float wmaxr(float v){
#pragma unroll
  for(int o=32;o;o>>=1) v = fmaxf(v, __shfl_xor(v,o,64));
  return v; }
DEVI float sigf(float x){ return 1.f/(1.f+__expf(-x)); }
// layernorm over 128 channels held as 2 values/lane across one 64-lane wave
DEVI float2 ln_wave(float2 x, const float* Wf, int ow, int ob, int lane){
  float mu = wsum(x.x + x.y) * (1.f/(float)CC);
  float dx = x.x - mu, dy = x.y - mu;
  float var = wsum(dx*dx + dy*dy) * (1.f/(float)CC);
  float rs = rsqrtf(var + 1e-5f);
  int c = 2*lane;
  return make_float2(dx*rs*Wf[ow+c] + Wf[ob+c], dy*rs*Wf[ow+c+1] + Wf[ob+c+1]);
}

struct Srcs { const void* p[22]; };

// K0: convert all weight tensors to f32 workspace (+ bf16 copies of GEMM weights)
__global__ void k_wcvt(Srcs s, float* __restrict__ ws,
                       unsigned short* __restrict__ wip, unsigned short* __restrict__ wob){
  bool isbf = bfmode(s.p[0]);
  int idx = blockIdx.x*256 + threadIdx.x;
  if(idx >= NW_RAW) return;
  int t = 0;
  while(t < 21 && idx >= c_woff[t+1]) t++;
  int j = idx - c_woff[t];
  if(j >= c_wsz[t]) return;  // padding gap
  float v = isbf ? bfu2f(((const unsigned short*)s.p[t])[j]) : ((const float*)s.p[t])[j];
  ws[idx] = v;
  if(t==11)      wip[j]         = f2bfu(v);   // in_proj_w
  else if(t==12) wip[65536+j]   = f2bfu(v);   // in_proj1_w
  else if(t==13) wip[98304+j]   = f2bfu(v);   // in_proj2_w
  else if(t==21) wob[j]         = f2bfu(v);   // out_w
}

// K1: fusion_resi = fusion + fusion_resi -> out1(f32); xf(bf16) = ln1(ln1(fr))
__global__ void k_fuse(const void* fus, const void* fres, const void* ln1raw,
                       float* __restrict__ ws, float* __restrict__ outf,
                       unsigned short* __restrict__ xbf){
  bool isbf = bfmode(ln1raw);
  int lane = threadIdx.x & 63, wv = threadIdx.x >> 6;
  int row = blockIdx.x*4 + wv;              // 16384 rows
  int base = row*CC;
  float2 a = ldin2(fus, base+2*lane, isbf);
  float2 b = ldin2(fres, base+2*lane, isbf);
  float2 fr = make_float2(a.x+b.x, a.y+b.y);
  *(float2*)(outf + BLC + base + 2*lane) = fr;      // output 1 = fusion_resi (f32)
  float2 y = ln_wave(fr, ws, OW_LN1W, OW_LN1B, lane);
  y = ln_wave(y, ws, OW_LN1W, OW_LN1B, lane);
  unsigned pk = (unsigned)f2bfu(y.x) | ((unsigned)f2bfu(y.y)<<16);
  *(unsigned*)&xbf[base + 2*lane] = pk;
}

// K2a: per-pixel channel mean/max of I1 (ten=0) and I2 (ten=1)
__global__ void k_meanmax(const void* I1, const void* I2, const void* ln1raw, float* __restrict__ ws){
  bool isbf = bfmode(ln1raw);
  int lane = threadIdx.x & 63, wv = threadIdx.x >> 6;
  int g = blockIdx.x*4 + wv;                // 32768 waves
  int ten = g & 1, row = g >> 1;
  const void* src = ten ? I2 : I1;
  float2 x = ldin2(src, row*CC + 2*lane, isbf);
  float sm = wsum(x.x + x.y) * (1.f/(float)CC);
  float mx = wmaxr(fmaxf(x.x, x.y));
  if(lane == 0){
    int b = row >> 12, l = row & 4095;
    float* mt = ws + O_M + (size_t)ten*(BB*2*LLn);
    mt[(size_t)b*2*LLn + l] = sm;
    mt[(size_t)b*2*LLn + LLn + l] = mx;
  }
}

// K2b: 5x5 conv (2ch->1) + sigmoid -> s1,s2
__global__ void k_spconv(float* __restrict__ ws){
  int idx = blockIdx.x*256 + threadIdx.x;   // 32768
  int ten = idx >> 14, b = (idx>>12)&3, l = idx & 4095;
  int h = l >> 6, w = l & 63;
  const float* mt = ws + O_M + (size_t)ten*(BB*2*LLn) + (size_t)b*2*LLn;
  float acc = 0.f;
  for(int ci=0; ci<2; ci++)
    for(int kh=0; kh<5; kh++){
      int hh = h + kh - 2; if((unsigned)hh >= 64u) continue;
      for(int kw=0; kw<5; kw++){
        int wn = w + kw - 2; if((unsigned)wn >= 64u) continue;
        acc += mt[(size_t)ci*LLn + hh*64 + wn] * ws[OW_SPW + ci*25 + kh*5 + kw];
      }
    }
  ws[O_S + (size_t)ten*(BB*LLn) + (size_t)b*LLn + l] = sigf(acc);
}

// K2c: e1(bf16) = ln2(ln2(I2*s2)), e2(bf16) = ln3(ln3(I1*s1))
__global__ void k_escale(const void* I1, const void* I2, const void* ln1raw,
                         float* __restrict__ ws, unsigned short* __restrict__ xbf){
  bool isbf = bfmode(ln1raw);
  int lane = threadIdx.x & 63, wv = threadIdx.x >> 6;
  int g = blockIdx.x*4 + wv;
  int ten = g & 1, row = g >> 1;            // ten0: e1 from I2; ten1: e2 from I1
  const void* src = ten ? I1 : I2;
  float sc = ws[O_S + (ten ? 0 : (size_t)BB*LLn) + row];
  float2 x = ldin2(src, row*CC + 2*lane, isbf);
  x.x *= sc; x.y *= sc;
  int ow = ten ? OW_LN3W : OW_LN2W, ob = ten ? OW_LN3B : OW_LN2B;
  float2 y = ln_wave(x, ws, ow, ob, lane);
  y = ln_wave(y, ws, ow, ob, lane);
  unsigned short* eb = xbf + (ten ? 2*BLC : BLC);
  unsigned pk = (unsigned)f2bfu(y.x) | ((unsigned)f2bfu(y.y)<<16);
  *(unsigned*)&eb[row*CC + 2*lane] = pk;
}

// K3: bf16 MFMA GEMM  out[m,n] = sum_k A[m,k]*W[n,k].
// 64x64 tile, 4 waves; wave w owns cols [w*16, w*16+16); 16x16x32 MFMA; XOR-swizzled LDS.
__global__ __launch_bounds__(256) void k_gemm_bf(const unsigned short* __restrict__ Abf,
    const unsigned short* __restrict__ Wbf, float* __restrict__ out,
    int Kd, int N, int mode, float* __restrict__ u, float* __restrict__ z){
  __shared__ unsigned short As[64*64];
  __shared__ unsigned short Bs[64*64];
  const int tid = threadIdx.x, lane = tid & 63, w = tid >> 6;
  const int n0 = blockIdx.x*64, m0 = blockIdx.y*64;
  const int g = lane >> 4, rlo = lane & 15;
  f32x4 acc[4];
#pragma unroll
  for(int i=0;i<4;i++) acc[i] = (f32x4){0.f,0.f,0.f,0.f};
  const int nk = Kd >> 6;
  for(int kt=0; kt<nk; kt++){
#pragma unroll
    for(int it=0; it<2; it++){               // stage 64x64 bf16 A and B tiles
      int idx = it*256 + tid, r = idx>>3, c = idx&7;
      uint4 av = *(const uint4*)&Abf[(size_t)(m0+r)*Kd + kt*64 + c*8];
      uint4 bv = *(const uint4*)&Wbf[(size_t)(n0+r)*Kd + kt*64 + c*8];
      int sw = (c*16) ^ ((r&7)<<4);          // bank swizzle (G4)
      *(uint4*)((char*)As + r*128 + sw) = av;
      *(uint4*)((char*)Bs + r*128 + sw) = bv;
    }
    __syncthreads();
#pragma unroll
    for(int ks=0; ks<2; ks++){
      int kb = ks*64 + g*16;
      int brow = w*16 + rlo;
      short8v bf = *(short8v*)((char*)Bs + brow*128 + (kb ^ ((rlo&7)<<4)));
#pragma unroll
      for(int rt=0; rt<4; rt++){
        int arow = rt*16 + rlo;
        short8v af = *(short8v*)((char*)As + arow*128 + (kb ^ ((rlo&7)<<4)));
        acc[rt] = __builtin_amdgcn_mfma_f32_16x16x32_bf16(af, bf, acc[rt], 0, 0, 0);
      }
    }
    __syncthreads();
  }
#pragma unroll
  for(int rt=0; rt<4; rt++){
#pragma unroll
    for(int j=0; j<4; j++){
      int m = m0 + rt*16 + g*4 + j;          // D: row=(lane>>4)*4+reg, col=lane&15 [m89]
      int n = n0 + w*16 + rlo;
      float val = acc[rt][j];
      if(mode == 0){
        out[(size_t)m*N + n] = val;
      } else {  // in-proj split: u0 / z (u1 no longer materialized; cxp mirrors u0)
        int b = m >> 12, l = m & (LLn-1);
        if(n < DI){
          u[((size_t)b*LLn + l)*DI + n] = val;
        } else {
          z[((size_t)b*LLn + l)*DI + (n-DI)] = val;
        }
      }
    }
  }
}

// K4+K5 fused: causal dwconv(K=4)+SiLU -> uc (global + LDS tile), then xproj from LDS.
// Block = 16 rows of one (s,b) stream; 256 threads (thread = d).
__global__ __launch_bounds__(256) void k_cxp(float* __restrict__ ws){
  __shared__ float ucl[16][260];
  __shared__ float wl[PP][260];
  int blk = blockIdx.x;                     // 4096
  int r0g = blk*16;
  int sb = r0g >> 12, s = sb >> 2, b = sb & 3;
  int l0 = r0g & 4095;
  int d = threadIdx.x;
  float4 cw = *(const float4*)&ws[OW_CVW + ((size_t)s*DI + d)*4];
  float cb = ws[OW_CVB + s*DI + d];
  const bool rev = (s == 1);                // stream 1 = reversed u0
  const float* ub = ws + O_U + (rev ? ((size_t)b*LLn)*DI : ((size_t)sb*LLn)*DI);
  // sliding causal window (l<0 -> 0)
  float w0, w1, w2;
  {
    int lm;
    lm = l0-3; w0 = (lm<0)?0.f:ub[(size_t)(rev?(LLn-1-lm):lm)*DI + d];
    lm = l0-2; w1 = (lm<0)?0.f:ub[(size_t)(rev?(LLn-1-lm):lm)*DI + d];
    lm = l0-1; w2 = (lm<0)?0.f:ub[(size_t)(rev?(LLn-1-lm):lm)*DI + d];
  }
#pragma unroll
  for(int r=0;r<16;r++){
    int l = l0 + r;
    float w3 = ub[(size_t)(rev?(LLn-1-l):l)*DI + d];
    float a = cb + cw.x*w0 + cw.y*w1 + cw.z*w2 + cw.w*w3;
    a *= sigf(a);                           // SiLU
    ucl[r][d] = a;
    ws[O_UC + ((size_t)sb*LLn + l)*DI + d] = a;
    w0 = w1; w1 = w2; w2 = w3;
  }
#pragma unroll
  for(int i=0;i<10;i++){
    int e4 = i*256 + threadIdx.x; int r = e4>>6, c4 = e4&63;
    *(float4*)&wl[r][c4*4] = *(const float4*)&ws[OW_XPW + ((size_t)s*PP + r)*DI + c4*4];
  }
  __syncthreads();
  int r = threadIdx.x & 15, ps = threadIdx.x >> 4;
  for(int pp=0; pp<3; pp++){
    int p = ps + pp*16;
    if(p < PP){
      float4 acc = make_float4(0,0,0,0);
#pragma unroll 8
      for(int c4=0;c4<64;c4++){
        float4 a = *(const float4*)&ucl[r][c4*4];
        float4 bq = *(const float4*)&wl[p][c4*4];
        acc.x += a.x*bq.x; acc.y += a.y*bq.y; acc.z += a.z*bq.z; acc.w += a.w*bq.w;
      }
      ws[O_PROJ + (size_t)(r0g+r)*PP + p] = acc.x+acc.y+acc.z+acc.w;
    }
  }
}

// K6/K8: chunk-parallel selective scan, vectorized LDS reads (ds_read_b128).
// PH3=false: local scan (h0=0) -> Hend, Sdt.  PH3=true: re-run with h_in, emit y.
template<bool PH3>
__global__ __launch_bounds__(256) void k_scan(float* __restrict__ ws){
  __shared__ float pl[CT*PP];
  int ch = blockIdx.x & (NCH-1), sb = blockIdx.x >> 6, s = sb >> 2;
  int d = threadIdx.x;
  size_t prow = ((size_t)sb*LLn + (size_t)ch*CT)*PP;
#pragma unroll
  for(int i=0;i<10;i++){ int idx = i*256 + threadIdx.x; pl[idx] = ws[O_PROJ + prow + idx]; }
  __syncthreads();
  float4 dtw0 = *(const float4*)&ws[OW_DTW + ((size_t)s*DI + d)*RR];
  float4 dtw1 = *(const float4*)&ws[OW_DTW + ((size_t)s*DI + d)*RR + 4];
  float dtb = ws[OW_DTB + s*DI + d];
  float an2[NS]; bool fast = true;
#pragma unroll
  for(int n=0;n<NS;n++){
    float a = -__expf(ws[OW_ALOG + ((size_t)s*DI + d)*NS + n]);
    an2[n] = a * 1.44269504f;
    fast = fast && (fabsf(a + (float)(n+1)) < 1e-4f);
  }
  float4 h0,h1,h2,h3;
  size_t hb = (((size_t)sb*NCH + ch)*DI + d)*NS;
  float* H = ws + O_H;
  if(PH3){
    h0 = *(const float4*)&H[hb];    h1 = *(const float4*)&H[hb+4];
    h2 = *(const float4*)&H[hb+8];  h3 = *(const float4*)&H[hb+12];
  } else {
    h0=h1=h2=h3=make_float4(0.f,0.f,0.f,0.f);
  }
  float dsk = PH3 ? ws[OW_DSK + s*DI + d] : 0.f;
  float sdt = 0.f;
  size_t ub = ((size_t)sb*LLn + (size_t)ch*CT)*DI + d;
  if(fast){
    for(int ll=0; ll<CT; ll++){
      const float* pr = &pl[ll*PP];
      float4 p0 = *(const float4*)pr, p1 = *(const float4*)(pr+4);
      float x = dtb + p0.x*dtw0.x + p0.y*dtw0.y + p0.z*dtw0.z + p0.w*dtw0.w
                    + p1.x*dtw1.x + p1.y*dtw1.y + p1.z*dtw1.z + p1.w*dtw1.w;
      float dt = (x > 15.f) ? x : __logf(1.f + __expf(x));
      float ut = ws[O_UC + ub + (size_t)ll*DI];
      float du = dt*ut;
      float e = __expf(-dt);
      float e2 = e*e, e4 = e2*e2;
      float4 da = make_float4(e, e2, e2*e, e4);   // e^1..e^4
      float4 B0 = *(const float4*)(pr+8),  B1 = *(const float4*)(pr+12),
             B2 = *(const float4*)(pr+16), B3 = *(const float4*)(pr+20);
      if(PH3){
        float4 C0 = *(const float4*)(pr+24), C1 = *(const float4*)(pr+28),
               C2 = *(const float4*)(pr+32), C3 = *(const float4*)(pr+36);
        float y;
        h0.x = fmaf(h0.x, da.x, du*B0.x); y  = h0.x*C0.x;
        h0.y = fmaf(h0.y, da.y, du*B0.y); y = fmaf(h0.y, C0.y, y);
        h0.z = fmaf(h0.z, da.z, du*B0.z); y = fmaf(h0.z, C0.z, y);
        h0.w = fmaf(h0.w, da.w, du*B0.w); y = fmaf(h0.w, C0.w, y);
        da.x *= e4; da.y *= e4; da.z *= e4; da.w *= e4;       // e^5..e^8
        h1.x = fmaf(h1.x, da.x, du*B1.x); y = fmaf(h1.x, C1.x, y);
        h1.y = fmaf(h1.y, da.y, du*B1.y); y = fmaf(h1.y, C1.y, y);
        h1.z = fmaf(h1.z, da.z, du*B1.z); y = fmaf(h1.z, C1.z, y);
        h1.w = fmaf(h1.w, da.w, du*B1.w); y = fmaf(h1.w, C1.w, y);
        da.x *= e4; da.y *= e4; da.z *= e4; da.w *= e4;       // e^9..e^12
        h2.x = fmaf(h2.x, da.x, du*B2.x); y = fmaf(h2.x, C2.x, y);
        h2.y = fmaf(h2.y, da.y, du*B2.y); y = fmaf(h2.y, C2.y, y);
        h2.z = fmaf(h2.z, da.z, du*B2.z); y = fmaf(h2.z, C2.z, y);
        h2.w = fmaf(h2.w, da.w, du*B2.w); y = fmaf(h2.w, C2.w, y);
        da.x *= e4; da.y *= e4; da.z *= e4; da.w *= e4;       // e^13..e^16
        h3.x = fmaf(h3.x, da.x, du*B3.x); y = fmaf(h3.x, C3.x, y);
        h3.y = fmaf(h3.y, da.y, du*B3.y); y = fmaf(h3.y, C3.y, y);
        h3.z = fmaf(h3.z, da.z, du*B3.z); y = fmaf(h3.z, C3.z, y);
        h3.w = fmaf(h3.w, da.w, du*B3.w); y = fmaf(h3.w, C3.w, y);
        ws[O_U + ub + (size_t)ll*DI] = y + ut*dsk;
      } else {
        h0.x = fmaf(h0.x, da.x, du*B0.x); h0.y = fmaf(h0.y, da.y, du*B0.y);
        h0.z = fmaf(h0.z, da.z, du*B0.z); h0.w = fmaf(h0.w, da.w, du*B0.w);
        da.x *= e4; da.y *= e4; da.z *= e4; da.w *= e4;
        h1.x = fmaf(h1.x, da.x, du*B1.x); h1.y = fmaf(h1.y, da.y, du*B1.y);
        h1.z = fmaf(h1.z, da.z, du*B1.z); h1.w = fmaf(h1.w, da.w, du*B1.w);
        da.x *= e4; da.y *= e4; da.z *= e4; da.w *= e4;
        h2.x = fmaf(h2.x, da.x, du*B2.x); h2.y = fmaf(h2.y, da.y, du*B2.y);
        h2.z = fmaf(h2.z, da.z, du*B2.z); h2.w = fmaf(h2.w, da.w, du*B2.w);
        da.x *= e4; da.y *= e4; da.z *= e4; da.w *= e4;
        h3.x = fmaf(h3.x, da.x, du*B3.x); h3.y = fmaf(h3.y, da.y, du*B3.y);
        h3.z = fmaf(h3.z, da.z, du*B3.z); h3.w = fmaf(h3.w, da.w, du*B3.w);
        sdt += dt;
      }
    }
  } else {
    float h[NS];
    h[0]=h0.x;h[1]=h0.y;h[2]=h0.z;h[3]=h0.w; h[4]=h1.x;h[5]=h1.y;h[6]=h1.z;h[7]=h1.w;
    h[8]=h2.x;h[9]=h2.y;h[10]=h2.z;h[11]=h2.w; h[12]=h3.x;h[13]=h3.y;h[14]=h3.z;h[15]=h3.w;
    for(int ll=0; ll<CT; ll++){
      const float* pr = &pl[ll*PP];
      float x = dtb;
      x += pr[0]*dtw0.x + pr[1]*dtw0.y + pr[2]*dtw0.z + pr[3]*dtw0.w;
      x += pr[4]*dtw1.x + pr[5]*dtw1.y + pr[6]*dtw1.z + pr[7]*dtw1.w;
      float dt = (x > 15.f) ? x : __logf(1.f + __expf(x));
      float ut = ws[O_UC + ub + (size_t)ll*DI];
      float du = dt*ut;
      if(PH3){
        float y = 0.f;
#pragma unroll
        for(int n=0;n<NS;n++){ float da = exp2f(an2[n]*dt); h[n] = h[n]*da + du*pr[RR+n]; y += h[n]*pr[RR+NS+n]; }
        ws[O_U + ub + (size_t)ll*DI] = y + ut*dsk;
      } else {
#pragma unroll
        for(int n=0;n<NS;n++){ float da = exp2f(an2[n]*dt); h[n] = h[n]*da + du*pr[RR+n]; }
        sdt += dt;
      }
    }
    h0=make_float4(h[0],h[1],h[2],h[3]); h1=make_float4(h[4],h[5],h[6],h[7]);
    h2=make_float4(h[8],h[9],h[10],h[11]); h3=make_float4(h[12],h[13],h[14],h[15]);
  }
  if(!PH3){
    *(float4*)&H[hb]    = h0; *(float4*)&H[hb+4]  = h1;
    *(float4*)&H[hb+8]  = h2; *(float4*)&H[hb+12] = h3;
    ws[O_SDT + ((size_t)sb*NCH + ch)*DI + d] = sdt;
  }
}

// K7: combine chunk boundary states: H (Hend) -> H (Hin), in place
__global__ void k_scan2(float* __restrict__ ws){
  int t = blockIdx.x*256 + threadIdx.x;     // 65536 = S*B*DI*NS
  int n = t & (NS-1), d = (t>>4) & (DI-1), sb = t >> 12, s = sb >> 2;
  float an2 = -__expf(ws[OW_ALOG + ((size_t)s*DI + d)*NS + n]) * 1.44269504f;
  float hin = 0.f;
  float* H = ws + O_H;
  for(int c=0;c<NCH;c++){
    size_t hi = (((size_t)sb*NCH + c)*DI + d)*NS + n;
    float he = H[hi];
    float sd = ws[O_SDT + ((size_t)sb*NCH + c)*DI + d];
    H[hi] = hin;
    hin = he + exp2f(an2*sd)*hin;
  }
}

// K9: combine 4 streams (stream1 re-reversed), gate with silu(z) -> gbf (bf16)
__global__ void k_gate(float* __restrict__ ws, unsigned short* __restrict__ gbf){
  int t = blockIdx.x*256 + threadIdx.x;     // BLD/4
  int d4 = t & 63, l = (t>>6)&4095, b = t>>18;
  int d0 = d4*4;
  const float* y = ws + O_U;
  size_t i0 = ((size_t)(0*BB+b)*LLn + l)*DI + d0;
  size_t i1 = ((size_t)(1*BB+b)*LLn + (LLn-1-l))*DI + d0;
  size_t i2 = ((size_t)(2*BB+b)*LLn + l)*DI + d0;
  size_t i3 = ((size_t)(3*BB+b)*LLn + l)*DI + d0;
  float4 a = *(const float4*)&y[i0], bb4 = *(const float4*)&y[i1];
  float4 c = *(const float4*)&y[i2], dd = *(const float4*)&y[i3];
  size_t zi = ((size_t)b*LLn + l)*DI + d0;
  float4 zv = *(const float4*)&ws[O_Z + zi];
  float4 g;
  g.x = (a.x+bb4.x+c.x+dd.x) * (zv.x*sigf(zv.x));
  g.y = (a.y+bb4.y+c.y+dd.y) * (zv.y*sigf(zv.y));
  g.z = (a.z+bb4.z+c.z+dd.z) * (zv.z*sigf(zv.z));
  g.w = (a.w+bb4.w+c.w+dd.w) * (zv.w*sigf(zv.w));
  uint2 pk;
  pk.x = (unsigned)f2bfu(g.x) | ((unsigned)f2bfu(g.y)<<16);
  pk.y = (unsigned)f2bfu(g.z) | ((unsigned)f2bfu(g.w)<<16);
  *(uint2*)&gbf[zi] = pk;
}

// K10: partial spatial mean/max of gf per (b, 128-row segment)
__global__ void k_redmm(float* __restrict__ ws){
  int b = blockIdx.x >> 5, seg = blockIdx.x & 31, c = threadIdx.x; // 128 threads
  const float* gf = ws + O_GF;
  float sm = 0.f, mx = -3e38f;
  size_t base = ((size_t)b*LLn + (size_t)seg*128)*CC + c;
  for(int i=0;i<128;i++){ float v = gf[base + (size_t)i*CC]; sm += v; mx = fmaxf(mx, v); }
  ws[O_PART + ((size_t)b*32 + seg)*CC + c] = sm;
  ws[O_PART + (size_t)BB*32*CC + ((size_t)b*32 + seg)*CC + c] = mx;
}

// K11: channel attention MLP -> sig[b,c]
__global__ void k_catt(float* __restrict__ ws){
  __shared__ float vm[CC], vx[CC], hm[32], hx[32];
  int b = blockIdx.x, c = threadIdx.x;      // 128 threads
  float sm = 0.f, mx = -3e38f;
  for(int seg=0;seg<32;seg++){
    sm += ws[O_PART + ((size_t)b*32+seg)*CC + c];
    mx = fmaxf(mx, ws[O_PART + (size_t)BB*32*CC + ((size_t)b*32+seg)*CC + c]);
  }
  vm[c] = sm * (1.f/(float)LLn); vx[c] = mx;
  __syncthreads();
  if(c < 32){
    float am = 0.f, ax = 0.f;
    for(int k=0;k<CC;k++){ float w1 = ws[OW_CAW1 + c*CC + k]; am += vm[k]*w1; ax += vx[k]*w1; }
    hm[c] = fmaxf(am, 0.f); hx[c] = fmaxf(ax, 0.f);
  }
  __syncthreads();
  float om = 0.f, ox = 0.f;
  for(int k=0;k<32;k++){ float w2 = ws[OW_CAW2 + c*32 + k]; om += hm[k]*w2; ox += hx[k]*w2; }
  ws[O_SIG + (size_t)b*CC + c] = sigf(om + ox);
}

// K12: f4 = gf^2*sig; out0 = dwconv3x3(f4) + dw_b + f4  (f32)
__global__ void k_final(float* __restrict__ ws, float* __restrict__ outf){
  int t = blockIdx.x*256 + threadIdx.x;     // B*L*C/4 = 524288
  int c4 = t & 31, l = (t>>5)&4095, b = t>>17;
  int h = l>>6, w = l&63;
  const float* gf = ws + O_GF;
  float4 sg = *(const float4*)&ws[O_SIG + (size_t)b*CC + c4*4];
  size_t rb = ((size_t)b*LLn)*CC;
  float4 gc = *(const float4*)&gf[rb + (size_t)l*CC + c4*4];
  float4 fc = make_float4(gc.x*gc.x*sg.x, gc.y*gc.y*sg.y, gc.z*gc.z*sg.z, gc.w*gc.w*sg.w);
  float4 acc = *(const float4*)&ws[OW_DWB + c4*4];
  float wv[4][9];
#pragma unroll
  for(int j=0;j<4;j++)
#pragma unroll
    for(int q=0;q<9;q++) wv[j][q] = ws[OW_DWW + (c4*4+j)*9 + q];
#pragma unroll
  for(int kh=0;kh<3;kh++){
    int hh = h + kh - 1; if((unsigned)hh >= 64u) continue;
#pragma unroll
    for(int kw=0;kw<3;kw++){
      int wn = w + kw - 1; if((unsigned)wn >= 64u) continue;
      float4 g = *(const float4*)&gf[rb + (size_t)(hh*64+wn)*CC + c4*4];
      int q = kh*3+kw;
      acc.x += wv[0][q]*g.x*g.x*sg.x;
      acc.y += wv[1][q]*g.y*g.y*sg.y;
      acc.z += wv[2][q]*g.z*g.z*sg.z;
      acc.w += wv[3][q]*g.w*g.w*sg.w;
    }
  }
  float4 o = make_float4(acc.x+fc.x, acc.y+fc.y, acc.z+fc.z, acc.w+fc.w);
  size_t ob = ((size_t)b*LLn + l)*CC + c4*4;
  *(float4*)&outf[ob] = o;                  // output 0 (f32)
}

extern "C" void kernel_launch(void* const* d_in, const int* in_sizes, int n_in,
                              void* d_out, int out_size, void* d_ws, size_t ws_size,
                              hipStream_t stream){
  (void)in_sizes; (void)n_in; (void)out_size;
  if(ws_size < WS_END*sizeof(float)) return;
  float* ws = (float*)d_ws;
  float* outf = (float*)d_out;              // f32 outputs (reference returns float32)
  const void* I1 = d_in[0]; const void* FRES = d_in[1];
  const void* I2 = d_in[2]; const void* FUS  = d_in[3];
  const void* LN1RAW = d_in[4];

  // bf16 aliases over dead-at-the-time f32 regions
  unsigned short* xbf   = (unsigned short*)(ws + O_H);    // xf [0,BLC), e1 [BLC,2BLC), e2 [2BLC,3BLC)
  unsigned short* gbf   = xbf;                            // gated, after scan (H dead)
  unsigned short* wipbf = (unsigned short*)(ws + O_GF);   // ipw | ip1w | ip2w (bf16)
  unsigned short* wobf  = (unsigned short*)(ws + O_PART); // out_w (bf16)

  Srcs sr;
  for(int i=0;i<22;i++) sr.p[i] = d_in[4+i];
  k_wcvt<<<(NW_RAW+255)/256, 256, 0, stream>>>(sr, ws, wipbf, wobf);
  k_fuse<<<4096, 256, 0, stream>>>(FUS, FRES, LN1RAW, ws, outf, xbf);
  k_meanmax<<<8192, 256, 0, stream>>>(I1, I2, LN1RAW, ws);
  k_spconv<<<128, 256, 0, stream>>>(ws);
  k_escale<<<8192, 256, 0, stream>>>(I1, I2, LN1RAW, ws, xbf);
  // MFMA GEMMs: in-proj (split u0/z), e1->u2, e2->u3
  k_gemm_bf<<<dim3(8,256), 256, 0, stream>>>(xbf,         wipbf,       nullptr,        128, 512, 1, ws+O_U, ws+O_Z);
  k_gemm_bf<<<dim3(4,256), 256, 0, stream>>>(xbf+BLC,     wipbf+65536, ws+O_U+2*BLD,   128, 256, 0, nullptr, nullptr);
  k_gemm_bf<<<dim3(4,256), 256, 0, stream>>>(xbf+2*BLC,   wipbf+98304, ws+O_U+3*BLD,   128, 256, 0, nullptr, nullptr);
  k_cxp<<<4096, 256, 0, stream>>>(ws);      // fused convsilu + xproj
  k_scan<false><<<SS*BB*NCH, 256, 0, stream>>>(ws);
  k_scan2<<<256, 256, 0, stream>>>(ws);
  k_scan<true><<<SS*BB*NCH, 256, 0, stream>>>(ws);
  k_gate<<<4096, 256, 0, stream>>>(ws, gbf);
  // out-proj: gf = g @ out_w.T  (reads gbf at O_H, writes O_GF over dead wipbf)
  k_gemm_bf<<<dim3(2,256), 256, 0, stream>>>(gbf, wobf, ws+O_GF, 256, 128, 0, nullptr, nullptr);
  k_redmm<<<128, 128, 0, stream>>>(ws);
  k_catt<<<4, 128, 0, stream>>>(ws);
  k_final<<<2048, 256, 0, stream>>>(ws, outf);
}

// Round 8
// 285.021 us; speedup vs baseline: 6.3230x; 1.0365x over previous
//
#include <hip/hip_runtime.h>

#define DEVI __device__ __forceinline__

static constexpr int BB=4, CC=128, LLn=4096, DI=256, NS=16, RR=8, SS=4;
static constexpr int PP = RR + 2*NS;            // 40
static constexpr int CT = 64, NCH = LLn/CT;     // scan chunking: 64 chunks of 64
static constexpr size_t BLC  = (size_t)BB*LLn*CC;    // 2,097,152
static constexpr size_t BLD  = (size_t)BB*LLn*DI;    // 4,194,304
static constexpr size_t SBLD = (size_t)SS*BLD;
static constexpr size_t SBLP = (size_t)SS*BB*LLn*PP;

// ---- weight offsets inside ws (floats), padded to multiples of 4 ----
static constexpr int OW_LN1W=0, OW_LN1B=128, OW_LN2W=256, OW_LN2B=384, OW_LN3W=512, OW_LN3B=640,
 OW_SPW=768, OW_CAW1=820, OW_CAW2=4916, OW_DWW=9012, OW_DWB=10164, OW_IPW=10292,
 OW_IP1W=75828, OW_IP2W=108596, OW_CVW=141364, OW_CVB=145460, OW_XPW=146484,
 OW_DTW=187444, OW_DTB=195636, OW_ALOG=196660, OW_DSK=213044, OW_OUTW=214068;
static constexpr int NW_RAW = 246836;   // last tensor end
static constexpr int NW_END = 246848;   // padded

__constant__ int c_woff[22] = {OW_LN1W,OW_LN1B,OW_LN2W,OW_LN2B,OW_LN3W,OW_LN3B,OW_SPW,OW_CAW1,
 OW_CAW2,OW_DWW,OW_DWB,OW_IPW,OW_IP1W,OW_IP2W,OW_CVW,OW_CVB,OW_XPW,OW_DTW,OW_DTB,OW_ALOG,
 OW_DSK,OW_OUTW};
__constant__ int c_wsz[22]  = {128,128,128,128,128,128,50,4096,4096,1152,128,65536,32768,32768,
 4096,1024,40960,8192,1024,16384,1024,32768};

// ---- workspace layout (float offsets) ----
static constexpr size_t O_XF   = NW_END;              // aliased: bf16 padded xproj weights (4x64x256 shorts)
static constexpr size_t O_E1   = O_XF + BLC;          // (unused)
static constexpr size_t O_E2   = O_E1 + BLC;          // (unused)
static constexpr size_t O_Z    = O_E2 + BLC;          // z from in-proj (f32)
static constexpr size_t O_U    = O_Z + BLD;           // u streams (u1 not materialized); later y
static constexpr size_t O_UC   = O_U + SBLD;          // aliased: uc in bf16 (SBLD shorts)
static constexpr size_t O_PROJ = O_UC + SBLD;
static constexpr size_t O_SDT  = O_PROJ + SBLP;
static constexpr size_t O_H    = O_SDT + (size_t)SS*BB*NCH*DI;   // scan state; ALSO aliased:
  // bf16 XBF [0,BLC) shorts, E1BF [BLC,2BLC), E2BF [2BLC,3BLC)  (dead before scan writes H)
  // bf16 GBF [0,BLD) shorts (written after scan, H dead)
static constexpr size_t O_M    = O_H + (size_t)SS*BB*NCH*DI*NS;
static constexpr size_t O_S    = O_M + 2*(size_t)BB*2*LLn;
static constexpr size_t O_GF   = O_S + 2*(size_t)BB*LLn;   // aliased: bf16 in-proj weights
static constexpr size_t O_PART = O_GF + BLC;               // aliased: bf16 out_w
static constexpr size_t O_SIG  = O_PART + 2*(size_t)BB*32*CC;
static constexpr size_t WS_END = O_SIG + (size_t)BB*CC;

typedef __attribute__((ext_vector_type(8))) short short8v;   // 8 bf16 (4 VGPR)
typedef __attribute__((ext_vector_type(4))) float f32x4;     // MFMA acc

// ---- helpers ----
DEVI float bfu2f(unsigned short s){ union{unsigned u; float f;} c; c.u = ((unsigned)s)<<16; return c.f; }
DEVI unsigned short f2bfu(float f){ union{float f; unsigned u;} c; c.f=f;
  unsigned r = c.u + 0x7FFFu + ((c.u>>16)&1u); return (unsigned short)(r>>16); }
DEVI bool bfmode(const void* ln1w){ return *(const unsigned*)ln1w == 0x3F803F80u; }
DEVI float2 ldin2(const void* p, int i, bool isbf){
  if(isbf){ unsigned v = *(const unsigned*)((const unsigned short*)p + i);
    return make_float2(bfu2f((unsigned short)(v & 0xFFFFu)), bfu2f((unsigned short)(v >> 16))); }
  const float* f = (const float*)p + i; return make_float2(f[0], f[1]);
}
DEVI float wsum(float v){
#pragma unroll
  for(int o=32;o;o>>=1) v += __shfl_xor(v,o,64);
  return v; }
DEVI float wmaxr(float v){
#pragma unroll
  for(int o=32;o;o>>=1) v = fmaxf(v, __shfl_xor(v,o,64));
  return v; }
DEVI float sigf(float x){ return 1.f/(1.f+__expf(-x)); }
// layernorm over 128 channels held as 2 values/lane across one 64-lane wave
DEVI float2 ln_wave(float2 x, const float* Wf, int ow, int ob, int lane){
  float mu = wsum(x.x + x.y) * (1.f/(float)CC);
  float dx = x.x - mu, dy = x.y - mu;
  float var = wsum(dx*dx + dy*dy) * (1.f/(float)CC);
  float rs = rsqrtf(var + 1e-5f);
  int c = 2*lane;
  return make_float2(dx*rs*Wf[ow+c] + Wf[ob+c], dy*rs*Wf[ow+c+1] + Wf[ob+c+1]);
}

struct Srcs { const void* p[22]; };

// K-1: zero the padded bf16 xproj weight block (4 streams x 64 rows x 256)
__global__ void k_xwpad(unsigned* __restrict__ xw32){
  int i = blockIdx.x*256 + threadIdx.x;     // 32768 uints = 65536 shorts
  xw32[i] = 0u;
}

// K0: convert all weight tensors to f32 workspace (+ bf16 copies of GEMM weights)
__global__ void k_wcvt(Srcs s, float* __restrict__ ws,
                       unsigned short* __restrict__ wip, unsigned short* __restrict__ wob,
                       unsigned short* __restrict__ xw){
  bool isbf = bfmode(s.p[0]);
  int idx = blockIdx.x*256 + threadIdx.x;
  if(idx >= NW_RAW) return;
  int t = 0;
  while(t < 21 && idx >= c_woff[t+1]) t++;
  int j = idx - c_woff[t];
  if(j >= c_wsz[t]) return;  // padding gap
  float v = isbf ? bfu2f(((const unsigned short*)s.p[t])[j]) : ((const float*)s.p[t])[j];
  ws[idx] = v;
  if(t==11)      wip[j]         = f2bfu(v);   // in_proj_w
  else if(t==12) wip[65536+j]   = f2bfu(v);   // in_proj1_w
  else if(t==13) wip[98304+j]   = f2bfu(v);   // in_proj2_w
  else if(t==21) wob[j]         = f2bfu(v);   // out_w
  else if(t==16){                             // xproj_w -> padded [s][64][256]
    int sid = j / 10240, rem = j % 10240;
    xw[((size_t)sid*64 + rem/256)*256 + (rem%256)] = f2bfu(v);
  }
}

// K1: fusion_resi = fusion + fusion_resi -> out1(f32); xf(bf16) = ln1(ln1(fr))
__global__ void k_fuse(const void* fus, const void* fres, const void* ln1raw,
                       float* __restrict__ ws, float* __restrict__ outf,
                       unsigned short* __restrict__ xbf){
  bool isbf = bfmode(ln1raw);
  int lane = threadIdx.x & 63, wv = threadIdx.x >> 6;
  int row = blockIdx.x*4 + wv;              // 16384 rows
  int base = row*CC;
  float2 a = ldin2(fus, base+2*lane, isbf);
  float2 b = ldin2(fres, base+2*lane, isbf);
  float2 fr = make_float2(a.x+b.x, a.y+b.y);
  *(float2*)(outf + BLC + base + 2*lane) = fr;      // output 1 = fusion_resi (f32)
  float2 y = ln_wave(fr, ws, OW_LN1W, OW_LN1B, lane);
  y = ln_wave(y, ws, OW_LN1W, OW_LN1B, lane);
  unsigned pk = (unsigned)f2bfu(y.x) | ((unsigned)f2bfu(y.y)<<16);
  *(unsigned*)&xbf[base + 2*lane] = pk;
}

// K2a: per-pixel channel mean/max of I1 (ten=0) and I2 (ten=1)
__global__ void k_meanmax(const void* I1, const void* I2, const void* ln1raw, float* __restrict__ ws){
  bool isbf = bfmode(ln1raw);
  int lane = threadIdx.x & 63, wv = threadIdx.x >> 6;
  int g = blockIdx.x*4 + wv;                // 32768 waves
  int ten = g & 1, row = g >> 1;
  const void* src = ten ? I2 : I1;
  float2 x = ldin2(src, row*CC + 2*lane, isbf);
  float sm = wsum(x.x + x.y) * (1.f/(float)CC);
  float mx = wmaxr(fmaxf(x.x, x.y));
  if(lane == 0){
    int b = row >> 12, l = row & 4095;
    float* mt = ws + O_M + (size_t)ten*(BB*2*LLn);
    mt[(size_t)b*2*LLn + l] = sm;
    mt[(size_t)b*2*LLn + LLn + l] = mx;
  }
}

// K2b: 5x5 conv (2ch->1) + sigmoid -> s1,s2
__global__ void k_spconv(float* __restrict__ ws){
  int idx = blockIdx.x*256 + threadIdx.x;   // 32768
  int ten = idx >> 14, b = (idx>>12)&3, l = idx & 4095;
  int h = l >> 6, w = l & 63;
  const float* mt = ws + O_M + (size_t)ten*(BB*2*LLn) + (size_t)b*2*LLn;
  float acc = 0.f;
  for(int ci=0; ci<2; ci++)
    for(int kh=0; kh<5; kh++){
      int hh = h + kh - 2; if((unsigned)hh >= 64u) continue;
      for(int kw=0; kw<5; kw++){
        int wn = w + kw - 2; if((unsigned)wn >= 64u) continue;
        acc += mt[(size_t)ci*LLn + hh*64 + wn] * ws[OW_SPW + ci*25 + kh*5 + kw];
      }
    }
  ws[O_S + (size_t)ten*(BB*LLn) + (size_t)b*LLn + l] = sigf(acc);
}

// K2c: e1(bf16) = ln2(ln2(I2*s2)), e2(bf16) = ln3(ln3(I1*s1))
__global__ void k_escale(const void* I1, const void* I2, const void* ln1raw,
                         float* __restrict__ ws, unsigned short* __restrict__ xbf){
  bool isbf = bfmode(ln1raw);
  int lane = threadIdx.x & 63, wv = threadIdx.x >> 6;
  int g = blockIdx.x*4 + wv;
  int ten = g & 1, row = g >> 1;            // ten0: e1 from I2; ten1: e2 from I1
  const void* src = ten ? I1 : I2;
  float sc = ws[O_S + (ten ? 0 : (size_t)BB*LLn) + row];
  float2 x = ldin2(src, row*CC + 2*lane, isbf);
  x.x *= sc; x.y *= sc;
  int ow = ten ? OW_LN3W : OW_LN2W, ob = ten ? OW_LN3B : OW_LN2B;
  float2 y = ln_wave(x, ws, ow, ob, lane);
  y = ln_wave(y, ws, ow, ob, lane);
  unsigned short* eb = xbf + (ten ? 2*BLC : BLC);
  unsigned pk = (unsigned)f2bfu(y.x) | ((unsigned)f2bfu(y.y)<<16);
  *(unsigned*)&eb[row*CC + 2*lane] = pk;
}

// K3: bf16 MFMA GEMM  out[m,n] = sum_k A[m,k]*W[n,k].
// 64x64 tile, 4 waves; wave w owns cols [w*16, w*16+16); 16x16x32 MFMA; XOR-swizzled LDS.
// mode 0: plain store (n<N guard). mode 1: in-proj split u0/z. mode 2: per-stream weight base (xproj).
__global__ __launch_bounds__(256) void k_gemm_bf(const unsigned short* __restrict__ Abf,
    const unsigned short* __restrict__ Wbf, float* __restrict__ out,
    int Kd, int N, int mode, float* __restrict__ u, float* __restrict__ z){
  __shared__ unsigned short As[64*64];
  __shared__ unsigned short Bs[64*64];
  const int tid = threadIdx.x, lane = tid & 63, w = tid >> 6;
  const int n0 = blockIdx.x*64, m0 = blockIdx.y*64;
  const int g = lane >> 4, rlo = lane & 15;
  if(mode == 2) Wbf += (size_t)(m0 >> 14) * (64*256);   // stream-s xproj weights
  f32x4 acc[4];
#pragma unroll
  for(int i=0;i<4;i++) acc[i] = (f32x4){0.f,0.f,0.f,0.f};
  const int nk = Kd >> 6;
  for(int kt=0; kt<nk; kt++){
#pragma unroll
    for(int it=0; it<2; it++){               // stage 64x64 bf16 A and B tiles
      int idx = it*256 + tid, r = idx>>3, c = idx&7;
      uint4 av = *(const uint4*)&Abf[(size_t)(m0+r)*Kd + kt*64 + c*8];
      uint4 bv = *(const uint4*)&Wbf[(size_t)(n0+r)*Kd + kt*64 + c*8];
      int sw = (c*16) ^ ((r&7)<<4);          // bank swizzle (G4)
      *(uint4*)((char*)As + r*128 + sw) = av;
      *(uint4*)((char*)Bs + r*128 + sw) = bv;
    }
    __syncthreads();
#pragma unroll
    for(int ks=0; ks<2; ks++){
      int kb = ks*64 + g*16;
      int brow = w*16 + rlo;
      short8v bf = *(short8v*)((char*)Bs + brow*128 + (kb ^ ((rlo&7)<<4)));
#pragma unroll
      for(int rt=0; rt<4; rt++){
        int arow = rt*16 + rlo;
        short8v af = *(short8v*)((char*)As + arow*128 + (kb ^ ((rlo&7)<<4)));
        acc[rt] = __builtin_amdgcn_mfma_f32_16x16x32_bf16(af, bf, acc[rt], 0, 0, 0);
      }
    }
    __syncthreads();
  }
#pragma unroll
  for(int rt=0; rt<4; rt++){
#pragma unroll
    for(int j=0; j<4; j++){
      int m = m0 + rt*16 + g*4 + j;          // D: row=(lane>>4)*4+reg, col=lane&15 [m89]
      int n = n0 + w*16 + rlo;
      float val = acc[rt][j];
      if(mode != 1){
        if(n < N) out[(size_t)m*N + n] = val;
      } else {  // in-proj split: u0 / z (u1 not materialized; conv mirrors u0)
        int b = m >> 12, l = m & (LLn-1);
        if(n < DI){
          u[((size_t)b*LLn + l)*DI + n] = val;
        } else {
          z[((size_t)b*LLn + l)*DI + (n-DI)] = val;
        }
      }
    }
  }
}

// K4: causal depthwise conv (K=4) + bias + SiLU -> uc (bf16). Stream 1 mirror-reads u0.
__global__ void k_conv(float* __restrict__ ws, unsigned short* __restrict__ ucbf){
  int t = blockIdx.x*256 + threadIdx.x;     // SBLD/4
  int d4 = t & 63, l = (t>>6)&4095, sb = t>>18, s = sb>>2, b = sb&3;
  int d0 = d4*4;
  const float* wp = ws + OW_CVW + ((size_t)s*DI + d0)*4;
  float wv[16];
#pragma unroll
  for(int q=0;q<16;q++) wv[q] = wp[q];
  float4 acc = *(const float4*)&ws[OW_CVB + s*DI + d0];
  const bool rev = (s == 1);
  const float* ub = ws + O_U + (rev ? ((size_t)b*LLn)*DI : ((size_t)sb*LLn)*DI);
#pragma unroll
  for(int k=0;k<4;k++){
    int lk = l - 3 + k;
    if(lk >= 0){
      int li = rev ? (LLn-1-lk) : lk;
      float4 uv = *(const float4*)&ub[(size_t)li*DI + d0];
      acc.x += wv[0*4+k]*uv.x; acc.y += wv[1*4+k]*uv.y;
      acc.z += wv[2*4+k]*uv.z; acc.w += wv[3*4+k]*uv.w;
    }
  }
  acc.x *= sigf(acc.x); acc.y *= sigf(acc.y); acc.z *= sigf(acc.z); acc.w *= sigf(acc.w);
  ushort4 o4; o4.x=f2bfu(acc.x); o4.y=f2bfu(acc.y); o4.z=f2bfu(acc.z); o4.w=f2bfu(acc.w);
  *(ushort4*)&ucbf[((size_t)sb*LLn + l)*DI + d0] = o4;
}

// K6/K8: chunk-parallel selective scan, vectorized LDS reads; uc read as bf16.
// PH3=false: local scan (h0=0) -> Hend, Sdt.  PH3=true: re-run with h_in, emit y.
template<bool PH3>
__global__ __launch_bounds__(256) void k_scan(float* __restrict__ ws,
                                              const unsigned short* __restrict__ ucbf){
  __shared__ float pl[CT*PP];
  int ch = blockIdx.x & (NCH-1), sb = blockIdx.x >> 6, s = sb >> 2;
  int d = threadIdx.x;
  size_t prow = ((size_t)sb*LLn + (size_t)ch*CT)*PP;
#pragma unroll
  for(int i=0;i<10;i++){ int idx = i*256 + threadIdx.x; pl[idx] = ws[O_PROJ + prow + idx]; }
  __syncthreads();
  float4 dtw0 = *(const float4*)&ws[OW_DTW + ((size_t)s*DI + d)*RR];
  float4 dtw1 = *(const float4*)&ws[OW_DTW + ((size_t)s*DI + d)*RR + 4];
  float dtb = ws[OW_DTB + s*DI + d];
  float an2[NS]; bool fast = true;
#pragma unroll
  for(int n=0;n<NS;n++){
    float a = -__expf(ws[OW_ALOG + ((size_t)s*DI + d)*NS + n]);
    an2[n] = a * 1.44269504f;
    fast = fast && (fabsf(a + (float)(n+1)) < 1e-4f);
  }
  float4 h0,h1,h2,h3;
  size_t hb = (((size_t)sb*NCH + ch)*DI + d)*NS;
  float* H = ws + O_H;
  if(PH3){
    h0 = *(const float4*)&H[hb];    h1 = *(const float4*)&H[hb+4];
    h2 = *(const float4*)&H[hb+8];  h3 = *(const float4*)&H[hb+12];
  } else {
    h0=h1=h2=h3=make_float4(0.f,0.f,0.f,0.f);
  }
  float dsk = PH3 ? ws[OW_DSK + s*DI + d] : 0.f;
  float sdt = 0.f;
  size_t ub = ((size_t)sb*LLn + (size_t)ch*CT)*DI + d;
  if(fast){
    for(int ll=0; ll<CT; ll++){
      const float* pr = &pl[ll*PP];
      float4 p0 = *(const float4*)pr, p1 = *(const float4*)(pr+4);
      float x = dtb + p0.x*dtw0.x + p0.y*dtw0.y + p0.z*dtw0.z + p0.w*dtw0.w
                    + p1.x*dtw1.x + p1.y*dtw1.y + p1.z*dtw1.z + p1.w*dtw1.w;
      float dt = (x > 15.f) ? x : __logf(1.f + __expf(x));
      float ut = bfu2f(ucbf[ub + (size_t)ll*DI]);
      float du = dt*ut;
      float e = __expf(-dt);
      float e2 = e*e, e4 = e2*e2;
      float4 da = make_float4(e, e2, e2*e, e4);   // e^1..e^4
      float4 B0 = *(const float4*)(pr+8),  B1 = *(const float4*)(pr+12),
             B2 = *(const float4*)(pr+16), B3 = *(const float4*)(pr+20);
      if(PH3){
        float4 C0 = *(const float4*)(pr+24), C1 = *(const float4*)(pr+28),
               C2 = *(const float4*)(pr+32), C3 = *(const float4*)(pr+36);
        float y;
        h0.x = fmaf(h0.x, da.x, du*B0.x); y  = h0.x*C0.x;
        h0.y = fmaf(h0.y, da.y, du*B0.y); y = fmaf(h0.y, C0.y, y);
        h0.z = fmaf(h0.z, da.z, du*B0.z); y = fmaf(h0.z, C0.z, y);
        h0.w = fmaf(h0.w, da.w, du*B0.w); y = fmaf(h0.w, C0.w, y);
        da.x *= e4; da.y *= e4; da.z *= e4; da.w *= e4;       // e^5..e^8
        h1.x = fmaf(h1.x, da.x, du*B1.x); y = fmaf(h1.x, C1.x, y);
        h1.y = fmaf(h1.y, da.y, du*B1.y); y = fmaf(h1.y, C1.y, y);
        h1.z = fmaf(h1.z, da.z, du*B1.z); y = fmaf(h1.z, C1.z, y);
        h1.w = fmaf(h1.w, da.w, du*B1.w); y = fmaf(h1.w, C1.w, y);
        da.x *= e4; da.y *= e4; da.z *= e4; da.w *= e4;       // e^9..e^12
        h2.x = fmaf(h2.x, da.x, du*B2.x); y = fmaf(h2.x, C2.x, y);
        h2.y = fmaf(h2.y, da.y, du*B2.y); y = fmaf(h2.y, C2.y, y);
        h2.z = fmaf(h2.z, da.z, du*B2.z); y = fmaf(h2.z, C2.z, y);
        h2.w = fmaf(h2.w, da.w, du*B2.w); y = fmaf(h2.w, C2.w, y);
        da.x *= e4; da.y *= e4; da.z *= e4; da.w *= e4;       // e^13..e^16
        h3.x = fmaf(h3.x, da.x, du*B3.x); y = fmaf(h3.x, C3.x, y);
        h3.y = fmaf(h3.y, da.y, du*B3.y); y = fmaf(h3.y, C3.y, y);
        h3.z = fmaf(h3.z, da.z, du*B3.z); y = fmaf(h3.z, C3.z, y);
        h3.w = fmaf(h3.w, da.w, du*B3.w); y = fmaf(h3.w, C3.w, y);
        ws[O_U + ub + (size_t)ll*DI] = y + ut*dsk;
      } else {
        h0.x = fmaf(h0.x, da.x, du*B0.x); h0.y = fmaf(h0.y, da.y, du*B0.y);
        h0.z = fmaf(h0.z, da.z, du*B0.z); h0.w = fmaf(h0.w, da.w, du*B0.w);
        da.x *= e4; da.y *= e4; da.z *= e4; da.w *= e4;
        h1.x = fmaf(h1.x, da.x, du*B1.x); h1.y = fmaf(h1.y, da.y, du*B1.y);
        h1.z = fmaf(h1.z, da.z, du*B1.z); h1.w = fmaf(h1.w, da.w, du*B1.w);
        da.x *= e4; da.y *= e4; da.z *= e4; da.w *= e4;
        h2.x = fmaf(h2.x, da.x, du*B2.x); h2.y = fmaf(h2.y, da.y, du*B2.y);
        h2.z = fmaf(h2.z, da.z, du*B2.z); h2.w = fmaf(h2.w, da.w, du*B2.w);
        da.x *= e4; da.y *= e4; da.z *= e4; da.w *= e4;
        h3.x = fmaf(h3.x, da.x, du*B3.x); h3.y = fmaf(h3.y, da.y, du*B3.y);
        h3.z = fmaf(h3.z, da.z, du*B3.z); h3.w = fmaf(h3.w, da.w, du*B3.w);
        sdt += dt;
      }
    }
  } else {
    float h[NS];
    h[0]=h0.x;h[1]=h0.y;h[2]=h0.z;h[3]=h0.w; h[4]=h1.x;h[5]=h1.y;h[6]=h1.z;h[7]=h1.w;
    h[8]=h2.x;h[9]=h2.y;h[10]=h2.z;h[11]=h2.w; h[12]=h3.x;h[13]=h3.y;h[14]=h3.z;h[15]=h3.w;
    for(int ll=0; ll<CT; ll++){
      const float* pr = &pl[ll*PP];
      float x = dtb;
      x += pr[0]*dtw0.x + pr[1]*dtw0.y + pr[2]*dtw0.z + pr[3]*dtw0.w;
      x += pr[4]*dtw1.x + pr[5]*dtw1.y + pr[6]*dtw1.z + pr[7]*dtw1.w;
      float dt = (x > 15.f) ? x : __logf(1.f + __expf(x));
      float ut = bfu2f(ucbf[ub + (size_t)ll*DI]);
      float du = dt*ut;
      if(PH3){
        float y = 0.f;
#pragma unroll
        for(int n=0;n<NS;n++){ float da = exp2f(an2[n]*dt); h[n] = h[n]*da + du*pr[RR+n]; y += h[n]*pr[RR+NS+n]; }
        ws[O_U + ub + (size_t)ll*DI] = y + ut*dsk;
      } else {
#pragma unroll
        for(int n=0;n<NS;n++){ float da = exp2f(an2[n]*dt); h[n] = h[n]*da + du*pr[RR+n]; }
        sdt += dt;
      }
    }
    h0=make_float4(h[0],h[1],h[2],h[3]); h1=make_float4(h[4],h[5],h[6],h[7]);
    h2=make_float4(h[8],h[9],h[10],h[11]); h3=make_float4(h[12],h[13],h[14],h[15]);
  }
  if(!PH3){
    *(float4*)&H[hb]    = h0; *(float4*)&H[hb+4]  = h1;
    *(float4*)&H[hb+8]  = h2; *(float4*)&H[hb+12] = h3;
    ws[O_SDT + ((size_t)sb*NCH + ch)*DI + d] = sdt;
  }
}

// K7: combine chunk boundary states: H (Hend) -> H (Hin), in place
__global__ void k_scan2(float* __restrict__ ws){
  int t = blockIdx.x*256 + threadIdx.x;     // 65536 = S*B*DI*NS
  int n = t & (NS-1), d = (t>>4) & (DI-1), sb = t >> 12, s = sb >> 2;
  float an2 = -__expf(ws[OW_ALOG + ((size_t)s*DI + d)*NS + n]) * 1.44269504f;
  float hin = 0.f;
  float* H = ws + O_H;
  for(int c=0;c<NCH;c++){
    size_t hi = (((size_t)sb*NCH + c)*DI + d)*NS + n;
    float he = H[hi];
    float sd = ws[O_SDT + ((size_t)sb*NCH + c)*DI + d];
    H[hi] = hin;
    hin = he + exp2f(an2*sd)*hin;
  }
}

// K9: combine 4 streams (stream1 re-reversed), gate with silu(z) -> gbf (bf16)
__global__ void k_gate(float* __restrict__ ws, unsigned short* __restrict__ gbf){
  int t = blockIdx.x*256 + threadIdx.x;     // BLD/4
  int d4 = t & 63, l = (t>>6)&4095, b = t>>18;
  int d0 = d4*4;
  const float* y = ws + O_U;
  size_t i0 = ((size_t)(0*BB+b)*LLn + l)*DI + d0;
  size_t i1 = ((size_t)(1*BB+b)*LLn + (LLn-1-l))*DI + d0;
  size_t i2 = ((size_t)(2*BB+b)*LLn + l)*DI + d0;
  size_t i3 = ((size_t)(3*BB+b)*LLn + l)*DI + d0;
  float4 a = *(const float4*)&y[i0], bb4 = *(const float4*)&y[i1];
  float4 c = *(const float4*)&y[i2], dd = *(const float4*)&y[i3];
  size_t zi = ((size_t)b*LLn + l)*DI + d0;
  float4 zv = *(const float4*)&ws[O_Z + zi];
  float4 g;
  g.x = (a.x+bb4.x+c.x+dd.x) * (zv.x*sigf(zv.x));
  g.y = (a.y+bb4.y+c.y+dd.y) * (zv.y*sigf(zv.y));
  g.z = (a.z+bb4.z+c.z+dd.z) * (zv.z*sigf(zv.z));
  g.w = (a.w+bb4.w+c.w+dd.w) * (zv.w*sigf(zv.w));
  uint2 pk;
  pk.x = (unsigned)f2bfu(g.x) | ((unsigned)f2bfu(g.y)<<16);
  pk.y = (unsigned)f2bfu(g.z) | ((unsigned)f2bfu(g.w)<<16);
  *(uint2*)&gbf[zi] = pk;
}

// K10: partial spatial mean/max of gf per (b, 128-row segment)
__global__ void k_redmm(float* __restrict__ ws){
  int b = blockIdx.x >> 5, seg = blockIdx.x & 31, c = threadIdx.x; // 128 threads
  const float* gf = ws + O_GF;
  float sm = 0.f, mx = -3e38f;
  size_t base = ((size_t)b*LLn + (size_t)seg*128)*CC + c;
  for(int i=0;i<128;i++){ float v = gf[base + (size_t)i*CC]; sm += v; mx = fmaxf(mx, v); }
  ws[O_PART + ((size_t)b*32 + seg)*CC + c] = sm;
  ws[O_PART + (size_t)BB*32*CC + ((size_t)b*32 + seg)*CC + c] = mx;
}

// K11: channel attention MLP -> sig[b,c]
__global__ void k_catt(float* __restrict__ ws){
  __shared__ float vm[CC], vx[CC], hm[32], hx[32];
  int b = blockIdx.x, c = threadIdx.x;      // 128 threads
  float sm = 0.f, mx = -3e38f;
  for(int seg=0;seg<32;seg++){
    sm += ws[O_PART + ((size_t)b*32+seg)*CC + c];
    mx = fmaxf(mx, ws[O_PART + (size_t)BB*32*CC + ((size_t)b*32+seg)*CC + c]);
  }
  vm[c] = sm * (1.f/(float)LLn); vx[c] = mx;
  __syncthreads();
  if(c < 32){
    float am = 0.f, ax = 0.f;
    for(int k=0;k<CC;k++){ float w1 = ws[OW_CAW1 + c*CC + k]; am += vm[k]*w1; ax += vx[k]*w1; }
    hm[c] = fmaxf(am, 0.f); hx[c] = fmaxf(ax, 0.f);
  }
  __syncthreads();
  float om = 0.f, ox = 0.f;
  for(int k=0;k<32;k++){ float w2 = ws[OW_CAW2 + c*32 + k]; om += hm[k]*w2; ox += hx[k]*w2; }
  ws[O_SIG + (size_t)b*CC + c] = sigf(om + ox);
}

// K12: f4 = gf^2*sig; out0 = dwconv3x3(f4) + dw_b + f4  (f32)
__global__ void k_final(float* __restrict__ ws, float* __restrict__ outf){
  int t = blockIdx.x*256 + threadIdx.x;     // B*L*C/4 = 524288
  int c4 = t & 31, l = (t>>5)&4095, b = t>>17;
  int h = l>>6, w = l&63;
  const float* gf = ws + O_GF;
  float4 sg = *(const float4*)&ws[O_SIG + (size_t)b*CC + c4*4];
  size_t rb = ((size_t)b*LLn)*CC;
  float4 gc = *(const float4*)&gf[rb + (size_t)l*CC + c4*4];
  float4 fc = make_float4(gc.x*gc.x*sg.x, gc.y*gc.y*sg.y, gc.z*gc.z*sg.z, gc.w*gc.w*sg.w);
  float4 acc = *(const float4*)&ws[OW_DWB + c4*4];
  float wv[4][9];
#pragma unroll
  for(int j=0;j<4;j++)
#pragma unroll
    for(int q=0;q<9;q++) wv[j][q] = ws[OW_DWW + (c4*4+j)*9 + q];
#pragma unroll
  for(int kh=0;kh<3;kh++){
    int hh = h + kh - 1; if((unsigned)hh >= 64u) continue;
#pragma unroll
    for(int kw=0;kw<3;kw++){
      int wn = w + kw - 1; if((unsigned)wn >= 64u) continue;
      float4 g = *(const float4*)&gf[rb + (size_t)(hh*64+wn)*CC + c4*4];
      int q = kh*3+kw;
      acc.x += wv[0][q]*g.x*g.x*sg.x;
      acc.y += wv[1][q]*g.y*g.y*sg.y;
      acc.z += wv[2][q]*g.z*g.z*sg.z;
      acc.w += wv[3][q]*g.w*g.w*sg.w;
    }
  }
  float4 o = make_float4(acc.x+fc.x, acc.y+fc.y, acc.z+fc.z, acc.w+fc.w);
  size_t ob = ((size_t)b*LLn + l)*CC + c4*4;
  *(float4*)&outf[ob] = o;                  // output 0 (f32)
}

extern "C" void kernel_launch(void* const* d_in, const int* in_sizes, int n_in,
                              void* d_out, int out_size, void* d_ws, size_t ws_size,
                              hipStream_t stream){
  (void)in_sizes; (void)n_in; (void)out_size;
  if(ws_size < WS_END*sizeof(float)) return;
  float* ws = (float*)d_ws;
  float* outf = (float*)d_out;              // f32 outputs (reference returns float32)
  const void* I1 = d_in[0]; const void* FRES = d_in[1];
  const void* I2 = d_in[2]; const void* FUS  = d_in[3];
  const void* LN1RAW = d_in[4];

  // bf16 aliases over dead-at-the-time f32 regions
  unsigned short* xbf   = (unsigned short*)(ws + O_H);    // xf [0,BLC), e1 [BLC,2BLC), e2 [2BLC,3BLC)
  unsigned short* gbf   = xbf;                            // gated, after scan (H dead)
  unsigned short* wipbf = (unsigned short*)(ws + O_GF);   // ipw | ip1w | ip2w (bf16)
  unsigned short* wobf  = (unsigned short*)(ws + O_PART); // out_w (bf16)
  unsigned short* xwbf  = (unsigned short*)(ws + O_XF);   // padded xproj weights [4][64][256] bf16
  unsigned short* ucbf  = (unsigned short*)(ws + O_UC);   // uc bf16 [S*B*L][256]

  Srcs sr;
  for(int i=0;i<22;i++) sr.p[i] = d_in[4+i];
  k_xwpad<<<128, 256, 0, stream>>>((unsigned*)xwbf);
  k_wcvt<<<(NW_RAW+255)/256, 256, 0, stream>>>(sr, ws, wipbf, wobf, xwbf);
  k_fuse<<<4096, 256, 0, stream>>>(FUS, FRES, LN1RAW, ws, outf, xbf);
  k_meanmax<<<8192, 256, 0, stream>>>(I1, I2, LN1RAW, ws);
  k_spconv<<<128, 256, 0, stream>>>(ws);
  k_escale<<<8192, 256, 0, stream>>>(I1, I2, LN1RAW, ws, xbf);
  // MFMA GEMMs: in-proj (split u0/z), e1->u2, e2->u3
  k_gemm_bf<<<dim3(8,256), 256, 0, stream>>>(xbf,         wipbf,       nullptr,        128, 512, 1, ws+O_U, ws+O_Z);
  k_gemm_bf<<<dim3(4,256), 256, 0, stream>>>(xbf+BLC,     wipbf+65536, ws+O_U+2*BLD,   128, 256, 0, nullptr, nullptr);
  k_gemm_bf<<<dim3(4,256), 256, 0, stream>>>(xbf+2*BLC,   wipbf+98304, ws+O_U+3*BLD,   128, 256, 0, nullptr, nullptr);
  k_conv<<<16384, 256, 0, stream>>>(ws, ucbf);
  // xproj as MFMA GEMM: proj[65536,40] = uc @ xw[s]^T (mode 2: per-stream weights)
  k_gemm_bf<<<dim3(1,1024), 256, 0, stream>>>(ucbf, xwbf, ws+O_PROJ, 256, 40, 2, nullptr, nullptr);
  k_scan<false><<<SS*BB*NCH, 256, 0, stream>>>(ws, ucbf);
  k_scan2<<<256, 256, 0, stream>>>(ws);
  k_scan<true><<<SS*BB*NCH, 256, 0, stream>>>(ws, ucbf);
  k_gate<<<4096, 256, 0, stream>>>(ws, gbf);
  // out-proj: gf = g @ out_w.T  (reads gbf at O_H, writes O_GF over dead wipbf)
  k_gemm_bf<<<dim3(2,256), 256, 0, stream>>>(gbf, wobf, ws+O_GF, 256, 128, 0, nullptr, nullptr);
  k_redmm<<<128, 128, 0, stream>>>(ws);
  k_catt<<<4, 128, 0, stream>>>(ws);
  k_final<<<2048, 256, 0, stream>>>(ws, outf);
}

// Round 9
// 241.035 us; speedup vs baseline: 7.4769x; 1.1825x over previous
//
#include <hip/hip_runtime.h>

#define DEVI __device__ __forceinline__

static constexpr int BB=4, CC=128, LLn=4096, DI=256, NS=16, RR=8, SS=4;
static constexpr int PP = RR + 2*NS;            // 40
static constexpr int CT = 64, NCH = LLn/CT;     // scan chunking: 64 chunks of 64
static constexpr size_t BLC  = (size_t)BB*LLn*CC;    // 2,097,152
static constexpr size_t BLD  = (size_t)BB*LLn*DI;    // 4,194,304
static constexpr size_t SBLD = (size_t)SS*BLD;
static constexpr size_t SBLP = (size_t)SS*BB*LLn*PP;

// ---- weight offsets inside ws (floats), padded to multiples of 4 ----
static constexpr int OW_LN1W=0, OW_LN1B=128, OW_LN2W=256, OW_LN2B=384, OW_LN3W=512, OW_LN3B=640,
 OW_SPW=768, OW_CAW1=820, OW_CAW2=4916, OW_DWW=9012, OW_DWB=10164, OW_IPW=10292,
 OW_IP1W=75828, OW_IP2W=108596, OW_CVW=141364, OW_CVB=145460, OW_XPW=146484,
 OW_DTW=187444, OW_DTB=195636, OW_ALOG=196660, OW_DSK=213044, OW_OUTW=214068;
static constexpr int NW_RAW = 246836;   // last tensor end
static constexpr int NW_END = 246848;   // padded

__constant__ int c_woff[22] = {OW_LN1W,OW_LN1B,OW_LN2W,OW_LN2B,OW_LN3W,OW_LN3B,OW_SPW,OW_CAW1,
 OW_CAW2,OW_DWW,OW_DWB,OW_IPW,OW_IP1W,OW_IP2W,OW_CVW,OW_CVB,OW_XPW,OW_DTW,OW_DTB,OW_ALOG,
 OW_DSK,OW_OUTW};
__constant__ int c_wsz[22]  = {128,128,128,128,128,128,50,4096,4096,1152,128,65536,32768,32768,
 4096,1024,40960,8192,1024,16384,1024,32768};

// ---- workspace layout (float offsets) ----
static constexpr size_t O_XF   = NW_END;              // aliased: bf16 padded xproj weights (4x64x256 shorts)
static constexpr size_t O_E1   = O_XF + BLC;          // (unused)
static constexpr size_t O_E2   = O_E1 + BLC;          // (unused)
static constexpr size_t O_Z    = O_E2 + BLC;          // z from in-proj (f32)
static constexpr size_t O_U    = O_Z + BLD;           // aliased: u streams bf16 (SBLD shorts); later y bf16
static constexpr size_t O_UC   = O_U + SBLD;          // aliased: uc in bf16 (SBLD shorts)
static constexpr size_t O_PROJ = O_UC + SBLD;
static constexpr size_t O_SDT  = O_PROJ + SBLP;
static constexpr size_t O_H    = O_SDT + (size_t)SS*BB*NCH*DI;   // scan state; ALSO aliased:
  // bf16 XBF [0,BLC) shorts, E1BF [BLC,2BLC), E2BF [2BLC,3BLC)  (dead before scan writes H)
  // bf16 GBF [0,BLD) shorts (written after scan, H dead)
static constexpr size_t O_M    = O_H + (size_t)SS*BB*NCH*DI*NS;
static constexpr size_t O_S    = O_M + 2*(size_t)BB*2*LLn;
static constexpr size_t O_GF   = O_S + 2*(size_t)BB*LLn;   // aliased: bf16 in-proj weights
static constexpr size_t O_PART = O_GF + BLC;               // aliased: bf16 out_w
static constexpr size_t O_SIG  = O_PART + 2*(size_t)BB*32*CC;
static constexpr size_t WS_END = O_SIG + (size_t)BB*CC;

typedef __attribute__((ext_vector_type(8))) short short8v;   // 8 bf16 (4 VGPR)
typedef __attribute__((ext_vector_type(4))) float f32x4;     // MFMA acc

// ---- helpers ----
DEVI float bfu2f(unsigned short s){ union{unsigned u; float f;} c; c.u = ((unsigned)s)<<16; return c.f; }
DEVI unsigned short f2bfu(float f){ union{float f; unsigned u;} c; c.f=f;
  unsigned r = c.u + 0x7FFFu + ((c.u>>16)&1u); return (unsigned short)(r>>16); }
DEVI float4 bf4(uint2 v){ return make_float4(bfu2f((unsigned short)(v.x&0xFFFFu)), bfu2f((unsigned short)(v.x>>16)),
                                             bfu2f((unsigned short)(v.y&0xFFFFu)), bfu2f((unsigned short)(v.y>>16))); }
DEVI bool bfmode(const void* ln1w){ return *(const unsigned*)ln1w == 0x3F803F80u; }
DEVI float2 ldin2(const void* p, int i, bool isbf){
  if(isbf){ unsigned v = *(const unsigned*)((const unsigned short*)p + i);
    return make_float2(bfu2f((unsigned short)(v & 0xFFFFu)), bfu2f((unsigned short)(v >> 16))); }
  const float* f = (const float*)p + i; return make_float2(f[0], f[1]);
}
DEVI float wsum(float v){
#pragma unroll
  for(int o=32;o;o>>=1) v += __shfl_xor(v,o,64);
  return v; }
DEVI float wmaxr(float v){
#pragma unroll
  for(int o=32;o;o>>=1) v = fmaxf(v, __shfl_xor(v,o,64));
  return v; }
DEVI float sigf(float x){ return 1.f/(1.f+__expf(-x)); }
// layernorm over 128 channels held as 2 values/lane across one 64-lane wave
DEVI float2 ln_wave(float2 x, const float* Wf, int ow, int ob, int lane){
  float mu = wsum(x.x + x.y) * (1.f/(float)CC);
  float dx = x.x - mu, dy = x.y - mu;
  float var = wsum(dx*dx + dy*dy) * (1.f/(float)CC);
  float rs = rsqrtf(var + 1e-5f);
  int c = 2*lane;
  return make_float2(dx*rs*Wf[ow+c] + Wf[ob+c], dy*rs*Wf[ow+c+1] + Wf[ob+c+1]);
}

struct Srcs { const void* p[22]; };

// K-1: zero the padded bf16 xproj weight block (4 streams x 64 rows x 256)
__global__ void k_xwpad(unsigned* __restrict__ xw32){
  int i = blockIdx.x*256 + threadIdx.x;     // 32768 uints = 65536 shorts
  xw32[i] = 0u;
}

// K0: convert all weight tensors to f32 workspace (+ bf16 copies of GEMM weights)
__global__ void k_wcvt(Srcs s, float* __restrict__ ws,
                       unsigned short* __restrict__ wip, unsigned short* __restrict__ wob,
                       unsigned short* __restrict__ xw){
  bool isbf = bfmode(s.p[0]);
  int idx = blockIdx.x*256 + threadIdx.x;
  if(idx >= NW_RAW) return;
  int t = 0;
  while(t < 21 && idx >= c_woff[t+1]) t++;
  int j = idx - c_woff[t];
  if(j >= c_wsz[t]) return;  // padding gap
  float v = isbf ? bfu2f(((const unsigned short*)s.p[t])[j]) : ((const float*)s.p[t])[j];
  ws[idx] = v;
  if(t==11)      wip[j]         = f2bfu(v);   // in_proj_w
  else if(t==12) wip[65536+j]   = f2bfu(v);   // in_proj1_w
  else if(t==13) wip[98304+j]   = f2bfu(v);   // in_proj2_w
  else if(t==21) wob[j]         = f2bfu(v);   // out_w
  else if(t==16){                             // xproj_w -> padded [s][64][256]
    int sid = j / 10240, rem = j % 10240;
    xw[((size_t)sid*64 + rem/256)*256 + (rem%256)] = f2bfu(v);
  }
}

// K1: fusion_resi = fusion + fusion_resi -> out1(f32); xf(bf16) = ln1(ln1(fr))
__global__ void k_fuse(const void* fus, const void* fres, const void* ln1raw,
                       float* __restrict__ ws, float* __restrict__ outf,
                       unsigned short* __restrict__ xbf){
  bool isbf = bfmode(ln1raw);
  int lane = threadIdx.x & 63, wv = threadIdx.x >> 6;
  int row = blockIdx.x*4 + wv;              // 16384 rows
  int base = row*CC;
  float2 a = ldin2(fus, base+2*lane, isbf);
  float2 b = ldin2(fres, base+2*lane, isbf);
  float2 fr = make_float2(a.x+b.x, a.y+b.y);
  *(float2*)(outf + BLC + base + 2*lane) = fr;      // output 1 = fusion_resi (f32)
  float2 y = ln_wave(fr, ws, OW_LN1W, OW_LN1B, lane);
  y = ln_wave(y, ws, OW_LN1W, OW_LN1B, lane);
  unsigned pk = (unsigned)f2bfu(y.x) | ((unsigned)f2bfu(y.y)<<16);
  *(unsigned*)&xbf[base + 2*lane] = pk;
}

// K2a: per-pixel channel mean/max of I1 (ten=0) and I2 (ten=1)
__global__ void k_meanmax(const void* I1, const void* I2, const void* ln1raw, float* __restrict__ ws){
  bool isbf = bfmode(ln1raw);
  int lane = threadIdx.x & 63, wv = threadIdx.x >> 6;
  int g = blockIdx.x*4 + wv;                // 32768 waves
  int ten = g & 1, row = g >> 1;
  const void* src = ten ? I2 : I1;
  float2 x = ldin2(src, row*CC + 2*lane, isbf);
  float sm = wsum(x.x + x.y) * (1.f/(float)CC);
  float mx = wmaxr(fmaxf(x.x, x.y));
  if(lane == 0){
    int b = row >> 12, l = row & 4095;
    float* mt = ws + O_M + (size_t)ten*(BB*2*LLn);
    mt[(size_t)b*2*LLn + l] = sm;
    mt[(size_t)b*2*LLn + LLn + l] = mx;
  }
}

// K2b: 5x5 conv (2ch->1) + sigmoid -> s1,s2
__global__ void k_spconv(float* __restrict__ ws){
  int idx = blockIdx.x*256 + threadIdx.x;   // 32768
  int ten = idx >> 14, b = (idx>>12)&3, l = idx & 4095;
  int h = l >> 6, w = l & 63;
  const float* mt = ws + O_M + (size_t)ten*(BB*2*LLn) + (size_t)b*2*LLn;
  float acc = 0.f;
  for(int ci=0; ci<2; ci++)
    for(int kh=0; kh<5; kh++){
      int hh = h + kh - 2; if((unsigned)hh >= 64u) continue;
      for(int kw=0; kw<5; kw++){
        int wn = w + kw - 2; if((unsigned)wn >= 64u) continue;
        acc += mt[(size_t)ci*LLn + hh*64 + wn] * ws[OW_SPW + ci*25 + kh*5 + kw];
      }
    }
  ws[O_S + (size_t)ten*(BB*LLn) + (size_t)b*LLn + l] = sigf(acc);
}

// K2c: e1(bf16) = ln2(ln2(I2*s2)), e2(bf16) = ln3(ln3(I1*s1))
__global__ void k_escale(const void* I1, const void* I2, const void* ln1raw,
                         float* __restrict__ ws, unsigned short* __restrict__ xbf){
  bool isbf = bfmode(ln1raw);
  int lane = threadIdx.x & 63, wv = threadIdx.x >> 6;
  int g = blockIdx.x*4 + wv;
  int ten = g & 1, row = g >> 1;            // ten0: e1 from I2; ten1: e2 from I1
  const void* src = ten ? I1 : I2;
  float sc = ws[O_S + (ten ? 0 : (size_t)BB*LLn) + row];
  float2 x = ldin2(src, row*CC + 2*lane, isbf);
  x.x *= sc; x.y *= sc;
  int ow = ten ? OW_LN3W : OW_LN2W, ob = ten ? OW_LN3B : OW_LN2B;
  float2 y = ln_wave(x, ws, ow, ob, lane);
  y = ln_wave(y, ws, ow, ob, lane);
  unsigned short* eb = xbf + (ten ? 2*BLC : BLC);
  unsigned pk = (unsigned)f2bfu(y.x) | ((unsigned)f2bfu(y.y)<<16);
  *(unsigned*)&eb[row*CC + 2*lane] = pk;
}

// K3: bf16 MFMA GEMM  out[m,n] = sum_k A[m,k]*W[n,k].
// 64x64 tile, 4 waves; wave w owns cols [w*16, w*16+16); 16x16x32 MFMA; XOR-swizzled LDS.
// mode 0: f32 out (n<N guard). mode 1: in-proj split u(bf16)/z(f32).
// mode 2: per-stream weight base, f32 out (xproj). mode 3: bf16 out.
__global__ __launch_bounds__(256) void k_gemm_bf(const unsigned short* __restrict__ Abf,
    const unsigned short* __restrict__ Wbf, float* __restrict__ out,
    int Kd, int N, int mode, unsigned short* __restrict__ ub16, float* __restrict__ z){
  __shared__ unsigned short As[64*64];
  __shared__ unsigned short Bs[64*64];
  const int tid = threadIdx.x, lane = tid & 63, w = tid >> 6;
  const int n0 = blockIdx.x*64, m0 = blockIdx.y*64;
  const int g = lane >> 4, rlo = lane & 15;
  if(mode == 2) Wbf += (size_t)(m0 >> 14) * (64*256);   // stream-s xproj weights
  f32x4 acc[4];
#pragma unroll
  for(int i=0;i<4;i++) acc[i] = (f32x4){0.f,0.f,0.f,0.f};
  const int nk = Kd >> 6;
  for(int kt=0; kt<nk; kt++){
#pragma unroll
    for(int it=0; it<2; it++){               // stage 64x64 bf16 A and B tiles
      int idx = it*256 + tid, r = idx>>3, c = idx&7;
      uint4 av = *(const uint4*)&Abf[(size_t)(m0+r)*Kd + kt*64 + c*8];
      uint4 bv = *(const uint4*)&Wbf[(size_t)(n0+r)*Kd + kt*64 + c*8];
      int sw = (c*16) ^ ((r&7)<<4);          // bank swizzle (G4)
      *(uint4*)((char*)As + r*128 + sw) = av;
      *(uint4*)((char*)Bs + r*128 + sw) = bv;
    }
    __syncthreads();
#pragma unroll
    for(int ks=0; ks<2; ks++){
      int kb = ks*64 + g*16;
      int brow = w*16 + rlo;
      short8v bf = *(short8v*)((char*)Bs + brow*128 + (kb ^ ((rlo&7)<<4)));
#pragma unroll
      for(int rt=0; rt<4; rt++){
        int arow = rt*16 + rlo;
        short8v af = *(short8v*)((char*)As + arow*128 + (kb ^ ((rlo&7)<<4)));
        acc[rt] = __builtin_amdgcn_mfma_f32_16x16x32_bf16(af, bf, acc[rt], 0, 0, 0);
      }
    }
    __syncthreads();
  }
#pragma unroll
  for(int rt=0; rt<4; rt++){
#pragma unroll
    for(int j=0; j<4; j++){
      int m = m0 + rt*16 + g*4 + j;          // D: row=(lane>>4)*4+reg, col=lane&15 [m89]
      int n = n0 + w*16 + rlo;
      float val = acc[rt][j];
      if(mode == 1){                          // in-proj split: u0 bf16 / z f32
        int b = m >> 12, l = m & (LLn-1);
        if(n < DI) ub16[((size_t)b*LLn + l)*DI + n] = f2bfu(val);
        else       z[((size_t)b*LLn + l)*DI + (n-DI)] = val;
      } else if(mode == 3){
        ub16[(size_t)m*N + n] = f2bfu(val);
      } else {
        if(n < N) out[(size_t)m*N + n] = val;
      }
    }
  }
}

// K4: causal depthwise conv (K=4) + bias + SiLU.  u bf16 -> uc bf16.
// Thread = 4 channels x 4 consecutive l (register sliding window). Stream 1 mirror-reads u0.
__global__ void k_conv(const float* __restrict__ ws, const unsigned short* __restrict__ ubf,
                       unsigned short* __restrict__ ucbf){
  int t = blockIdx.x*256 + threadIdx.x;     // 1,048,576 threads
  int dg = t & 63, lg = (t>>6) & 1023, sb = t >> 16, s = sb >> 2, b = sb & 3;
  int d0 = dg*4, l0 = lg*4;
  float wv[16];
  const float* wp = ws + OW_CVW + ((size_t)s*DI + d0)*4;
#pragma unroll
  for(int q=0;q<16;q++) wv[q] = wp[q];
  float4 cb = *(const float4*)&ws[OW_CVB + s*DI + d0];
  const bool rev = (s == 1);
  const unsigned short* ub = ubf + (rev ? (size_t)b*LLn : (size_t)sb*LLn)*DI;
  float4 w0, w1, w2;
  {
    int lm;
    lm = l0-3; w0 = (lm<0)?make_float4(0,0,0,0):bf4(*(const uint2*)&ub[(size_t)(rev?(LLn-1-lm):lm)*DI + d0]);
    lm = l0-2; w1 = (lm<0)?make_float4(0,0,0,0):bf4(*(const uint2*)&ub[(size_t)(rev?(LLn-1-lm):lm)*DI + d0]);
    lm = l0-1; w2 = (lm<0)?make_float4(0,0,0,0):bf4(*(const uint2*)&ub[(size_t)(rev?(LLn-1-lm):lm)*DI + d0]);
  }
#pragma unroll
  for(int r=0;r<4;r++){
    int l = l0 + r;
    float4 w3 = bf4(*(const uint2*)&ub[(size_t)(rev?(LLn-1-l):l)*DI + d0]);
    float4 acc;
    acc.x = cb.x + wv[0]*w0.x + wv[1]*w1.x + wv[2]*w2.x + wv[3]*w3.x;
    acc.y = cb.y + wv[4]*w0.y + wv[5]*w1.y + wv[6]*w2.y + wv[7]*w3.y;
    acc.z = cb.z + wv[8]*w0.z + wv[9]*w1.z + wv[10]*w2.z + wv[11]*w3.z;
    acc.w = cb.w + wv[12]*w0.w + wv[13]*w1.w + wv[14]*w2.w + wv[15]*w3.w;
    acc.x *= sigf(acc.x); acc.y *= sigf(acc.y); acc.z *= sigf(acc.z); acc.w *= sigf(acc.w);
    ushort4 o4; o4.x=f2bfu(acc.x); o4.y=f2bfu(acc.y); o4.z=f2bfu(acc.z); o4.w=f2bfu(acc.w);
    *(ushort4*)&ucbf[((size_t)sb*LLn + l)*DI + d0] = o4;
    w0 = w1; w1 = w2; w2 = w3;
  }
}

// K6/K8: chunk-parallel selective scan, vectorized LDS reads; uc read as bf16.
// PH3=false: local scan (h0=0) -> Hend, Sdt.  PH3=true: re-run with h_in, emit y (bf16).
template<bool PH3>
__global__ __launch_bounds__(256) void k_scan(float* __restrict__ ws,
                                              const unsigned short* __restrict__ ucbf){
  __shared__ float pl[CT*PP];
  int ch = blockIdx.x & (NCH-1), sb = blockIdx.x >> 6, s = sb >> 2;
  int d = threadIdx.x;
  size_t prow = ((size_t)sb*LLn + (size_t)ch*CT)*PP;
#pragma unroll
  for(int i=0;i<10;i++){ int idx = i*256 + threadIdx.x; pl[idx] = ws[O_PROJ + prow + idx]; }
  __syncthreads();
  unsigned short* ybf = (unsigned short*)(ws + O_U);   // y overwrites dead u (bf16)
  float4 dtw0 = *(const float4*)&ws[OW_DTW + ((size_t)s*DI + d)*RR];
  float4 dtw1 = *(const float4*)&ws[OW_DTW + ((size_t)s*DI + d)*RR + 4];
  float dtb = ws[OW_DTB + s*DI + d];
  float an2[NS]; bool fast = true;
#pragma unroll
  for(int n=0;n<NS;n++){
    float a = -__expf(ws[OW_ALOG + ((size_t)s*DI + d)*NS + n]);
    an2[n] = a * 1.44269504f;
    fast = fast && (fabsf(a + (float)(n+1)) < 1e-4f);
  }
  float4 h0,h1,h2,h3;
  size_t hb = (((size_t)sb*NCH + ch)*DI + d)*NS;
  float* H = ws + O_H;
  if(PH3){
    h0 = *(const float4*)&H[hb];    h1 = *(const float4*)&H[hb+4];
    h2 = *(const float4*)&H[hb+8];  h3 = *(const float4*)&H[hb+12];
  } else {
    h0=h1=h2=h3=make_float4(0.f,0.f,0.f,0.f);
  }
  float dsk = PH3 ? ws[OW_DSK + s*DI + d] : 0.f;
  float sdt = 0.f;
  size_t ub = ((size_t)sb*LLn + (size_t)ch*CT)*DI + d;
  if(fast){
    for(int ll=0; ll<CT; ll++){
      const float* pr = &pl[ll*PP];
      float4 p0 = *(const float4*)pr, p1 = *(const float4*)(pr+4);
      float x = dtb + p0.x*dtw0.x + p0.y*dtw0.y + p0.z*dtw0.z + p0.w*dtw0.w
                    + p1.x*dtw1.x + p1.y*dtw1.y + p1.z*dtw1.z + p1.w*dtw1.w;
      float dt = (x > 15.f) ? x : __logf(1.f + __expf(x));
      float ut = bfu2f(ucbf[ub + (size_t)ll*DI]);
      float du = dt*ut;
      float e = __expf(-dt);
      float e2 = e*e, e4 = e2*e2;
      float4 da = make_float4(e, e2, e2*e, e4);   // e^1..e^4
      float4 B0 = *(const float4*)(pr+8),  B1 = *(const float4*)(pr+12),
             B2 = *(const float4*)(pr+16), B3 = *(const float4*)(pr+20);
      if(PH3){
        float4 C0 = *(const float4*)(pr+24), C1 = *(const float4*)(pr+28),
               C2 = *(const float4*)(pr+32), C3 = *(const float4*)(pr+36);
        float y;
        h0.x = fmaf(h0.x, da.x, du*B0.x); y  = h0.x*C0.x;
        h0.y = fmaf(h0.y, da.y, du*B0.y); y = fmaf(h0.y, C0.y, y);
        h0.z = fmaf(h0.z, da.z, du*B0.z); y = fmaf(h0.z, C0.z, y);
        h0.w = fmaf(h0.w, da.w, du*B0.w); y = fmaf(h0.w, C0.w, y);
        da.x *= e4; da.y *= e4; da.z *= e4; da.w *= e4;       // e^5..e^8
        h1.x = fmaf(h1.x, da.x, du*B1.x); y = fmaf(h1.x, C1.x, y);
        h1.y = fmaf(h1.y, da.y, du*B1.y); y = fmaf(h1.y, C1.y, y);
        h1.z = fmaf(h1.z, da.z, du*B1.z); y = fmaf(h1.z, C1.z, y);
        h1.w = fmaf(h1.w, da.w, du*B1.w); y = fmaf(h1.w, C1.w, y);
        da.x *= e4; da.y *= e4; da.z *= e4; da.w *= e4;       // e^9..e^12
        h2.x = fmaf(h2.x, da.x, du*B2.x); y = fmaf(h2.x, C2.x, y);
        h2.y = fmaf(h2.y, da.y, du*B2.y); y = fmaf(h2.y, C2.y, y);
        h2.z = fmaf(h2.z, da.z, du*B2.z); y = fmaf(h2.z, C2.z, y);
        h2.w = fmaf(h2.w, da.w, du*B2.w); y = fmaf(h2.w, C2.w, y);
        da.x *= e4; da.y *= e4; da.z *= e4; da.w *= e4;       // e^13..e^16
        h3.x = fmaf(h3.x, da.x, du*B3.x); y = fmaf(h3.x, C3.x, y);
        h3.y = fmaf(h3.y, da.y, du*B3.y); y = fmaf(h3.y, C3.y, y);
        h3.z = fmaf(h3.z, da.z, du*B3.z); y = fmaf(h3.z, C3.z, y);
        h3.w = fmaf(h3.w, da.w, du*B3.w); y = fmaf(h3.w, C3.w, y);
        ybf[ub + (size_t)ll*DI] = f2bfu(y + ut*dsk);
      } else {
        h0.x = fmaf(h0.x, da.x, du*B0.x); h0.y = fmaf(h0.y, da.y, du*B0.y);
        h0.z = fmaf(h0.z, da.z, du*B0.z); h0.w = fmaf(h0.w, da.w, du*B0.w);
        da.x *= e4; da.y *= e4; da.z *= e4; da.w *= e4;
        h1.x = fmaf(h1.x, da.x, du*B1.x); h1.y = fmaf(h1.y, da.y, du*B1.y);
        h1.z = fmaf(h1.z, da.z, du*B1.z); h1.w = fmaf(h1.w, da.w, du*B1.w);
        da.x *= e4; da.y *= e4; da.z *= e4; da.w *= e4;
        h2.x = fmaf(h2.x, da.x, du*B2.x); h2.y = fmaf(h2.y, da.y, du*B2.y);
        h2.z = fmaf(h2.z, da.z, du*B2.z); h2.w = fmaf(h2.w, da.w, du*B2.w);
        da.x *= e4; da.y *= e4; da.z *= e4; da.w *= e4;
        h3.x = fmaf(h3.x, da.x, du*B3.x); h3.y = fmaf(h3.y, da.y, du*B3.y);
        h3.z = fmaf(h3.z, da.z, du*B3.z); h3.w = fmaf(h3.w, da.w, du*B3.w);
        sdt += dt;
      }
    }
  } else {
    float h[NS];
    h[0]=h0.x;h[1]=h0.y;h[2]=h0.z;h[3]=h0.w; h[4]=h1.x;h[5]=h1.y;h[6]=h1.z;h[7]=h1.w;
    h[8]=h2.x;h[9]=h2.y;h[10]=h2.z;h[11]=h2.w; h[12]=h3.x;h[13]=h3.y;h[14]=h3.z;h[15]=h3.w;
    for(int ll=0; ll<CT; ll++){
      const float* pr = &pl[ll*PP];
      float x = dtb;
      x += pr[0]*dtw0.x + pr[1]*dtw0.y + pr[2]*dtw0.z + pr[3]*dtw0.w;
      x += pr[4]*dtw1.x + pr[5]*dtw1.y + pr[6]*dtw1.z + pr[7]*dtw1.w;
      float dt = (x > 15.f) ? x : __logf(1.f + __expf(x));
      float ut = bfu2f(ucbf[ub + (size_t)ll*DI]);
      float du = dt*ut;
      if(PH3){
        float y = 0.f;
#pragma unroll
        for(int n=0;n<NS;n++){ float da = exp2f(an2[n]*dt); h[n] = h[n]*da + du*pr[RR+n]; y += h[n]*pr[RR+NS+n]; }
        ybf[ub + (size_t)ll*DI] = f2bfu(y + ut*dsk);
      } else {
#pragma unroll
        for(int n=0;n<NS;n++){ float da = exp2f(an2[n]*dt); h[n] = h[n]*da + du*pr[RR+n]; }
        sdt += dt;
      }
    }
    h0=make_float4(h[0],h[1],h[2],h[3]); h1=make_float4(h[4],h[5],h[6],h[7]);
    h2=make_float4(h[8],h[9],h[10],h[11]); h3=make_float4(h[12],h[13],h[14],h[15]);
  }
  if(!PH3){
    *(float4*)&H[hb]    = h0; *(float4*)&H[hb+4]  = h1;
    *(float4*)&H[hb+8]  = h2; *(float4*)&H[hb+12] = h3;
    ws[O_SDT + ((size_t)sb*NCH + ch)*DI + d] = sdt;
  }
}

// K7: combine chunk boundary states: H (Hend) -> H (Hin), in place
__global__ void k_scan2(float* __restrict__ ws){
  int t = blockIdx.x*256 + threadIdx.x;     // 65536 = S*B*DI*NS
  int n = t & (NS-1), d = (t>>4) & (DI-1), sb = t >> 12, s = sb >> 2;
  float an2 = -__expf(ws[OW_ALOG + ((size_t)s*DI + d)*NS + n]) * 1.44269504f;
  float hin = 0.f;
  float* H = ws + O_H;
  for(int c=0;c<NCH;c++){
    size_t hi = (((size_t)sb*NCH + c)*DI + d)*NS + n;
    float he = H[hi];
    float sd = ws[O_SDT + ((size_t)sb*NCH + c)*DI + d];
    H[hi] = hin;
    hin = he + exp2f(an2*sd)*hin;
  }
}

// K9: combine 4 streams (stream1 re-reversed, bf16 y), gate with silu(z) -> gbf (bf16)
__global__ void k_gate(float* __restrict__ ws, unsigned short* __restrict__ gbf){
  int t = blockIdx.x*256 + threadIdx.x;     // BLD/4
  int d4 = t & 63, l = (t>>6)&4095, b = t>>18;
  int d0 = d4*4;
  const unsigned short* ybf = (const unsigned short*)(ws + O_U);
  size_t i0 = ((size_t)(0*BB+b)*LLn + l)*DI + d0;
  size_t i1 = ((size_t)(1*BB+b)*LLn + (LLn-1-l))*DI + d0;
  size_t i2 = ((size_t)(2*BB+b)*LLn + l)*DI + d0;
  size_t i3 = ((size_t)(3*BB+b)*LLn + l)*DI + d0;
  float4 a = bf4(*(const uint2*)&ybf[i0]);
  float4 bb4 = bf4(*(const uint2*)&ybf[i1]);
  float4 c = bf4(*(const uint2*)&ybf[i2]);
  float4 dd = bf4(*(const uint2*)&ybf[i3]);
  size_t zi = ((size_t)b*LLn + l)*DI + d0;
  float4 zv = *(const float4*)&ws[O_Z + zi];
  float4 g;
  g.x = (a.x+bb4.x+c.x+dd.x) * (zv.x*sigf(zv.x));
  g.y = (a.y+bb4.y+c.y+dd.y) * (zv.y*sigf(zv.y));
  g.z = (a.z+bb4.z+c.z+dd.z) * (zv.z*sigf(zv.z));
  g.w = (a.w+bb4.w+c.w+dd.w) * (zv.w*sigf(zv.w));
  uint2 pk;
  pk.x = (unsigned)f2bfu(g.x) | ((unsigned)f2bfu(g.y)<<16);
  pk.y = (unsigned)f2bfu(g.z) | ((unsigned)f2bfu(g.w)<<16);
  *(uint2*)&gbf[zi] = pk;
}

// K10: partial spatial mean/max of gf per (b, 128-row segment)
__global__ void k_redmm(float* __restrict__ ws){
  int b = blockIdx.x >> 5, seg = blockIdx.x & 31, c = threadIdx.x; // 128 threads
  const float* gf = ws + O_GF;
  float sm = 0.f, mx = -3e38f;
  size_t base = ((size_t)b*LLn + (size_t)seg*128)*CC + c;
  for(int i=0;i<128;i++){ float v = gf[base + (size_t)i*CC]; sm += v; mx = fmaxf(mx, v); }
  ws[O_PART + ((size_t)b*32 + seg)*CC + c] = sm;
  ws[O_PART + (size_t)BB*32*CC + ((size_t)b*32 + seg)*CC + c] = mx;
}

// K11: channel attention MLP -> sig[b,c]
__global__ void k_catt(float* __restrict__ ws){
  __shared__ float vm[CC], vx[CC], hm[32], hx[32];
  int b = blockIdx.x, c = threadIdx.x;      // 128 threads
  float sm = 0.f, mx = -3e38f;
  for(int seg=0;seg<32;seg++){
    sm += ws[O_PART + ((size_t)b*32+seg)*CC + c];
    mx = fmaxf(mx, ws[O_PART + (size_t)BB*32*CC + ((size_t)b*32+seg)*CC + c]);
  }
  vm[c] = sm * (1.f/(float)LLn); vx[c] = mx;
  __syncthreads();
  if(c < 32){
    float am = 0.f, ax = 0.f;
    for(int k=0;k<CC;k++){ float w1 = ws[OW_CAW1 + c*CC + k]; am += vm[k]*w1; ax += vx[k]*w1; }
    hm[c] = fmaxf(am, 0.f); hx[c] = fmaxf(ax, 0.f);
  }
  __syncthreads();
  float om = 0.f, ox = 0.f;
  for(int k=0;k<32;k++){ float w2 = ws[OW_CAW2 + c*32 + k]; om += hm[k]*w2; ox += hx[k]*w2; }
  ws[O_SIG + (size_t)b*CC + c] = sigf(om + ox);
}

// K12: f4 = gf^2*sig; out0 = dwconv3x3(f4) + dw_b + f4  (f32)
__global__ void k_final(float* __restrict__ ws, float* __restrict__ outf){
  int t = blockIdx.x*256 + threadIdx.x;     // B*L*C/4 = 524288
  int c4 = t & 31, l = (t>>5)&4095, b = t>>17;
  int h = l>>6, w = l&63;
  const float* gf = ws + O_GF;
  float4 sg = *(const float4*)&ws[O_SIG + (size_t)b*CC + c4*4];
  size_t rb = ((size_t)b*LLn)*CC;
  float4 gc = *(const float4*)&gf[rb + (size_t)l*CC + c4*4];
  float4 fc = make_float4(gc.x*gc.x*sg.x, gc.y*gc.y*sg.y, gc.z*gc.z*sg.z, gc.w*gc.w*sg.w);
  float4 acc = *(const float4*)&ws[OW_DWB + c4*4];
  float wv[4][9];
#pragma unroll
  for(int j=0;j<4;j++)
#pragma unroll
    for(int q=0;q<9;q++) wv[j][q] = ws[OW_DWW + (c4*4+j)*9 + q];
#pragma unroll
  for(int kh=0;kh<3;kh++){
    int hh = h + kh - 1; if((unsigned)hh >= 64u) continue;
#pragma unroll
    for(int kw=0;kw<3;kw++){
      int wn = w + kw - 1; if((unsigned)wn >= 64u) continue;
      float4 g = *(const float4*)&gf[rb + (size_t)(hh*64+wn)*CC + c4*4];
      int q = kh*3+kw;
      acc.x += wv[0][q]*g.x*g.x*sg.x;
      acc.y += wv[1][q]*g.y*g.y*sg.y;
      acc.z += wv[2][q]*g.z*g.z*sg.z;
      acc.w += wv[3][q]*g.w*g.w*sg.w;
    }
  }
  float4 o = make_float4(acc.x+fc.x, acc.y+fc.y, acc.z+fc.z, acc.w+fc.w);
  size_t ob = ((size_t)b*LLn + l)*CC + c4*4;
  *(float4*)&outf[ob] = o;                  // output 0 (f32)
}

extern "C" void kernel_launch(void* const* d_in, const int* in_sizes, int n_in,
                              void* d_out, int out_size, void* d_ws, size_t ws_size,
                              hipStream_t stream){
  (void)in_sizes; (void)n_in; (void)out_size;
  if(ws_size < WS_END*sizeof(float)) return;
  float* ws = (float*)d_ws;
  float* outf = (float*)d_out;              // f32 outputs (reference returns float32)
  const void* I1 = d_in[0]; const void* FRES = d_in[1];
  const void* I2 = d_in[2]; const void* FUS  = d_in[3];
  const void* LN1RAW = d_in[4];

  // bf16 aliases over dead-at-the-time f32 regions
  unsigned short* xbf   = (unsigned short*)(ws + O_H);    // xf [0,BLC), e1 [BLC,2BLC), e2 [2BLC,3BLC)
  unsigned short* gbf   = xbf;                            // gated, after scan (H dead)
  unsigned short* wipbf = (unsigned short*)(ws + O_GF);   // ipw | ip1w | ip2w (bf16)
  unsigned short* wobf  = (unsigned short*)(ws + O_PART); // out_w (bf16)
  unsigned short* xwbf  = (unsigned short*)(ws + O_XF);   // padded xproj weights [4][64][256] bf16
  unsigned short* ucbf  = (unsigned short*)(ws + O_UC);   // uc bf16 [S*B*L][256]
  unsigned short* ubf   = (unsigned short*)(ws + O_U);    // u bf16 [S*B*L][256]; later y bf16

  Srcs sr;
  for(int i=0;i<22;i++) sr.p[i] = d_in[4+i];
  k_xwpad<<<128, 256, 0, stream>>>((unsigned*)xwbf);
  k_wcvt<<<(NW_RAW+255)/256, 256, 0, stream>>>(sr, ws, wipbf, wobf, xwbf);
  k_fuse<<<4096, 256, 0, stream>>>(FUS, FRES, LN1RAW, ws, outf, xbf);
  k_meanmax<<<8192, 256, 0, stream>>>(I1, I2, LN1RAW, ws);
  k_spconv<<<128, 256, 0, stream>>>(ws);
  k_escale<<<8192, 256, 0, stream>>>(I1, I2, LN1RAW, ws, xbf);
  // MFMA GEMMs: in-proj (split u0 bf16 / z f32), e1->u2 bf16, e2->u3 bf16
  k_gemm_bf<<<dim3(8,256), 256, 0, stream>>>(xbf,         wipbf,       nullptr,      128, 512, 1, ubf,        ws+O_Z);
  k_gemm_bf<<<dim3(4,256), 256, 0, stream>>>(xbf+BLC,     wipbf+65536, nullptr,      128, 256, 3, ubf+2*BLD,  nullptr);
  k_gemm_bf<<<dim3(4,256), 256, 0, stream>>>(xbf+2*BLC,   wipbf+98304, nullptr,      128, 256, 3, ubf+3*BLD,  nullptr);
  k_conv<<<4096, 256, 0, stream>>>(ws, ubf, ucbf);
  // xproj as MFMA GEMM: proj[65536,40] = uc @ xw[s]^T (mode 2: per-stream weights)
  k_gemm_bf<<<dim3(1,1024), 256, 0, stream>>>(ucbf, xwbf, ws+O_PROJ, 256, 40, 2, nullptr, nullptr);
  k_scan<false><<<SS*BB*NCH, 256, 0, stream>>>(ws, ucbf);
  k_scan2<<<256, 256, 0, stream>>>(ws);
  k_scan<true><<<SS*BB*NCH, 256, 0, stream>>>(ws, ucbf);
  k_gate<<<4096, 256, 0, stream>>>(ws, gbf);
  // out-proj: gf = g @ out_w.T  (reads gbf at O_H, writes O_GF over dead wipbf)
  k_gemm_bf<<<dim3(2,256), 256, 0, stream>>>(gbf, wobf, ws+O_GF, 256, 128, 0, nullptr, nullptr);
  k_redmm<<<128, 128, 0, stream>>>(ws);
  k_catt<<<4, 128, 0, stream>>>(ws);
  k_final<<<2048, 256, 0, stream>>>(ws, outf);
}